// Round 1
// baseline (2772.141 us; speedup 1.0000x reference)
//
#include <hip/hip_runtime.h>
#include <cstdint>

// GNN: 2-layer GraphSAGE (mean aggr, L2-normalize) + BatchNorm(train) + ReLU.
// N=100000 nodes, E=800000 edges, C: 128 -> 128 -> 47.
//
// Pipeline (all fp32):
//  1. scatter1: agg1[dst] += x[src] (atomics), cnt[dst] += 1
//  2. gemm1:    s1 = L2norm_rows( (agg1/cnt) @ w1l^T + b1l + x @ w1r^T )
//  3. bn_stats/bn_final/bn_apply: h = relu(gamma*(s1-mean)*rsqrt(var+eps)+beta)
//  4. gemm2:    y2 = h @ w2l^T ; rbuf = h @ w2r^T    (aggregate AFTER the
//               linear map -> only 47 channels of atomics instead of 128)
//  5. scatter2: agg2[dst] += y2[src]
//  6. final:    out = L2norm_rows( agg2/cnt + b2l + rbuf )

static __device__ __forceinline__ float warp_sum64(float v) {
    #pragma unroll
    for (int off = 32; off > 0; off >>= 1) v += __shfl_xor(v, off, 64);
    return v;
}

// ---- transpose weights into wT1[k][128] (k<128: w1l, else w1r) and
// ---- wT2[k][96] (j<47: w2l, j<94: w2r, else 0)
__global__ __launch_bounds__(256) void k_wt(
        const float* __restrict__ w1l, const float* __restrict__ w1r,
        const float* __restrict__ w2l, const float* __restrict__ w2r,
        float* __restrict__ wT1, float* __restrict__ wT2) {
    int idx = blockIdx.x * 256 + threadIdx.x;
    if (idx < 256 * 128) {
        int k = idx >> 7, j = idx & 127;
        wT1[idx] = (k < 128) ? w1l[j * 128 + k] : w1r[j * 128 + (k - 128)];
    } else if (idx < 256 * 128 + 128 * 96) {
        int i2 = idx - 256 * 128;
        int k = i2 / 96, j = i2 % 96;
        float v = 0.f;
        if (j < 47)      v = w2l[j * 128 + k];
        else if (j < 94) v = w2r[(j - 47) * 128 + k];
        wT2[i2] = v;
    }
}

// ---- layer-1 scatter: 32 threads/edge, float4 atomics over 128 channels
__global__ __launch_bounds__(256) void k_scatter1(
        const float* __restrict__ x, const int* __restrict__ ei,
        float* __restrict__ agg1, float* __restrict__ cnt, int nE) {
    int gid = blockIdx.x * 256 + threadIdx.x;
    int e = gid >> 5, q = gid & 31;
    if (e >= nE) return;
    int s = ei[e];
    int d = ei[nE + e];
    float4 v = *(const float4*)(x + (size_t)s * 128 + q * 4);
    float* a = agg1 + (size_t)d * 128 + q * 4;
    atomicAdd(a + 0, v.x);
    atomicAdd(a + 1, v.y);
    atomicAdd(a + 2, v.z);
    atomicAdd(a + 3, v.w);
    if (q == 0) atomicAdd(cnt + d, 1.0f);
}

// ---- GEMM1: 64 rows/block, 256 threads: lane owns (row r, 32 channels).
// K=256 (agg-half then x-half), x tile staged transposed+swizzled in LDS,
// weights read wave-uniformly from wT1 (scalar loads).
__global__ __launch_bounds__(256) void k_gemm1(
        const float* __restrict__ x, const float* __restrict__ agg,
        const float* __restrict__ cnt, const float* __restrict__ wT,
        const float* __restrict__ b1l, float* __restrict__ s1, int n) {
    __shared__ float xst[128][64];
    __shared__ float red[4][64];
    int t = threadIdx.x;
    int r = t & 63;
    int cg = t >> 6;          // wave id -> channel group
    int j0 = cg * 32;
    int r0 = blockIdx.x * 64;

    float acc[32];
    #pragma unroll
    for (int u = 0; u < 32; ++u) acc[u] = 0.f;

    for (int half = 0; half < 2; ++half) {
        __syncthreads();
        // stage 64 rows x 128 k, transposed: xst[k][(row + (k>>2)) & 63]
        #pragma unroll
        for (int it = 0; it < 8; ++it) {
            int idx = t + it * 256;     // 0..2047
            int row = idx >> 5;         // 0..63
            int c4  = idx & 31;         // float4 index within row
            int gr = r0 + row;
            float4 v = make_float4(0.f, 0.f, 0.f, 0.f);
            if (gr < n) {
                const float* src = (half == 0 ? agg : x) + (size_t)gr * 128 + c4 * 4;
                v = *(const float4*)src;
                if (half == 0) {
                    float ic = 1.0f / fmaxf(cnt[gr], 1.0f);
                    v.x *= ic; v.y *= ic; v.z *= ic; v.w *= ic;
                }
            }
            int kb = c4 * 4;
            int sr = (row + c4) & 63;
            xst[kb + 0][sr] = v.x;
            xst[kb + 1][sr] = v.y;
            xst[kb + 2][sr] = v.z;
            xst[kb + 3][sr] = v.w;
        }
        __syncthreads();
        for (int k = 0; k < 128; ++k) {
            float xv = xst[k][(r + (k >> 2)) & 63];
            const float4* wrow = (const float4*)(wT + (size_t)(half * 128 + k) * 128 + j0);
            #pragma unroll
            for (int q = 0; q < 8; ++q) {
                float4 wv = wrow[q];
                acc[q * 4 + 0] = fmaf(xv, wv.x, acc[q * 4 + 0]);
                acc[q * 4 + 1] = fmaf(xv, wv.y, acc[q * 4 + 1]);
                acc[q * 4 + 2] = fmaf(xv, wv.z, acc[q * 4 + 2]);
                acc[q * 4 + 3] = fmaf(xv, wv.w, acc[q * 4 + 3]);
            }
        }
    }

    // bias + row L2 norm (128 channels spread over 4 waves at same r)
    float partial = 0.f;
    #pragma unroll
    for (int u = 0; u < 32; ++u) {
        acc[u] += b1l[j0 + u];
        partial += acc[u] * acc[u];
    }
    red[cg][r] = partial;
    __syncthreads();
    float nrm2 = red[0][r] + red[1][r] + red[2][r] + red[3][r];
    float inv = 1.0f / fmaxf(sqrtf(nrm2), 1e-12f);
    int gr = r0 + r;
    if (gr < n) {
        float4* out4 = (float4*)(s1 + (size_t)gr * 128 + j0);
        #pragma unroll
        for (int q = 0; q < 8; ++q) {
            float4 o;
            o.x = acc[q * 4 + 0] * inv;
            o.y = acc[q * 4 + 1] * inv;
            o.z = acc[q * 4 + 2] * inv;
            o.w = acc[q * 4 + 3] * inv;
            out4[q] = o;
        }
    }
}

// ---- BN batch stats: per-channel sum and sumsq (channel = tid & 127 invariant)
__global__ __launch_bounds__(256) void k_bn_stats(
        const float* __restrict__ s1, float* __restrict__ stats, int n) {
    int t = threadIdx.x;
    float sv = 0.f, qv = 0.f;
    size_t total = (size_t)n * 128;
    for (size_t i = (size_t)blockIdx.x * 256 + t; i < total; i += (size_t)gridDim.x * 256) {
        float v = s1[i];
        sv += v;
        qv += v * v;
    }
    __shared__ float ls[256], lq[256];
    ls[t] = sv; lq[t] = qv;
    __syncthreads();
    if (t < 128) {
        atomicAdd(&stats[t],       ls[t] + ls[t + 128]);
        atomicAdd(&stats[128 + t], lq[t] + lq[t + 128]);
    }
}

__global__ void k_bn_final(float* stats, const float* __restrict__ gamma,
                           const float* __restrict__ beta, int n) {
    int c = threadIdx.x;  // 128 threads
    float s = stats[c], q = stats[128 + c];
    float fn = (float)n;
    float mean = s / fn;
    float var = q / fn - mean * mean;   // biased variance, matches reference
    float istd = rsqrtf(var + 1e-5f);
    float a = gamma[c] * istd;
    float b = beta[c] - mean * a;
    stats[c] = a;
    stats[128 + c] = b;
}

__global__ __launch_bounds__(256) void k_bn_apply(
        float* __restrict__ s1, const float* __restrict__ stats, int n) {
    __shared__ float a[128], b[128];
    int t = threadIdx.x;
    if (t < 128) { a[t] = stats[t]; b[t] = stats[128 + t]; }
    __syncthreads();
    int i = blockIdx.x * 256 + t;
    if (i >= n * 32) return;
    float4 v = ((const float4*)s1)[i];
    int c0 = (i & 31) * 4;
    v.x = fmaxf(fmaf(a[c0 + 0], v.x, b[c0 + 0]), 0.f);
    v.y = fmaxf(fmaf(a[c0 + 1], v.y, b[c0 + 1]), 0.f);
    v.z = fmaxf(fmaf(a[c0 + 2], v.z, b[c0 + 2]), 0.f);
    v.w = fmaxf(fmaf(a[c0 + 3], v.w, b[c0 + 3]), 0.f);
    ((float4*)s1)[i] = v;
}

// ---- GEMM2: h[N,128] x wT2[128][96] -> y2[N,47] (lin_l part, pre-aggregation)
//      and rbuf[N,47] (lin_r part). 64 rows/block, lane owns 24 channels.
__global__ __launch_bounds__(256) void k_gemm2(
        const float* __restrict__ h, const float* __restrict__ wT2,
        float* __restrict__ y2, float* __restrict__ rbuf, int n) {
    __shared__ float xst[128][64];
    int t = threadIdx.x;
    int r = t & 63;
    int cg = t >> 6;
    int j0 = cg * 24;
    int r0 = blockIdx.x * 64;

    float acc[24];
    #pragma unroll
    for (int u = 0; u < 24; ++u) acc[u] = 0.f;

    #pragma unroll
    for (int it = 0; it < 8; ++it) {
        int idx = t + it * 256;
        int row = idx >> 5;
        int c4  = idx & 31;
        int gr = r0 + row;
        float4 v = make_float4(0.f, 0.f, 0.f, 0.f);
        if (gr < n) v = *(const float4*)(h + (size_t)gr * 128 + c4 * 4);
        int kb = c4 * 4;
        int sr = (row + c4) & 63;
        xst[kb + 0][sr] = v.x;
        xst[kb + 1][sr] = v.y;
        xst[kb + 2][sr] = v.z;
        xst[kb + 3][sr] = v.w;
    }
    __syncthreads();
    for (int k = 0; k < 128; ++k) {
        float xv = xst[k][(r + (k >> 2)) & 63];
        const float4* wrow = (const float4*)(wT2 + (size_t)k * 96 + j0);
        #pragma unroll
        for (int q = 0; q < 6; ++q) {
            float4 wv = wrow[q];
            acc[q * 4 + 0] = fmaf(xv, wv.x, acc[q * 4 + 0]);
            acc[q * 4 + 1] = fmaf(xv, wv.y, acc[q * 4 + 1]);
            acc[q * 4 + 2] = fmaf(xv, wv.z, acc[q * 4 + 2]);
            acc[q * 4 + 3] = fmaf(xv, wv.w, acc[q * 4 + 3]);
        }
    }
    int gr = r0 + r;
    if (gr >= n) return;
    #pragma unroll
    for (int u = 0; u < 24; ++u) {
        int j = j0 + u;
        if (j < 47)      y2[(size_t)gr * 47 + j] = acc[u];
        else if (j < 94) rbuf[(size_t)gr * 47 + (j - 47)] = acc[u];
    }
}

// ---- layer-2 scatter: 12 threads/edge, 4 channels each (47 total)
__global__ __launch_bounds__(256) void k_scatter2(
        const float* __restrict__ y2, const int* __restrict__ ei,
        float* __restrict__ agg2, int nE) {
    int gid = blockIdx.x * 256 + threadIdx.x;
    int e = gid / 12, q = gid - e * 12;
    if (e >= nE) return;
    int s = ei[e];
    int d = ei[nE + e];
    int c0 = q * 4;
    const float* ys = y2 + (size_t)s * 47;
    float* ad = agg2 + (size_t)d * 47;
    #pragma unroll
    for (int u = 0; u < 4; ++u) {
        int c = c0 + u;
        if (c < 47) atomicAdd(ad + c, ys[c]);
    }
}

// ---- combine + row L2 norm -> out. One wave per row.
__global__ __launch_bounds__(256) void k_final(
        const float* __restrict__ agg2, const float* __restrict__ rbuf,
        const float* __restrict__ cnt, const float* __restrict__ b2l,
        float* __restrict__ out, int n) {
    int t = threadIdx.x;
    int lane = t & 63, w = t >> 6;
    int row = blockIdx.x * 4 + w;
    float v = 0.f;
    bool valid = (row < n) && (lane < 47);
    if (valid) {
        float ic = 1.0f / fmaxf(cnt[row], 1.0f);
        v = agg2[(size_t)row * 47 + lane] * ic + b2l[lane] + rbuf[(size_t)row * 47 + lane];
    }
    float ss = warp_sum64(v * v);
    float inv = 1.0f / fmaxf(sqrtf(ss), 1e-12f);
    if (valid) out[(size_t)row * 47 + lane] = v * inv;
}

extern "C" void kernel_launch(void* const* d_in, const int* in_sizes, int n_in,
                              void* d_out, int out_size, void* d_ws, size_t ws_size,
                              hipStream_t stream) {
    const float* x     = (const float*)d_in[0];
    const int*   ei    = (const int*)d_in[1];
    const float* w1l   = (const float*)d_in[2];
    const float* b1l   = (const float*)d_in[3];
    const float* w1r   = (const float*)d_in[4];
    const float* gamma = (const float*)d_in[5];
    const float* beta  = (const float*)d_in[6];
    const float* w2l   = (const float*)d_in[7];
    const float* b2l   = (const float*)d_in[8];
    const float* w2r   = (const float*)d_in[9];
    float* out = (float*)d_out;

    int n  = in_sizes[0] / 128;   // 100000
    int nE = in_sizes[1] / 2;     // 800000

    // workspace layout (floats):
    // [0, n)            cnt
    // [n, 129n)         agg1   (reused: y2 = first 47n, rbuf = next 47n)
    // [129n, 257n)      bufB   (s1 / h; reused: agg2 = first 47n)
    // [257n, +32768)    wT1
    // [.. +12288)       wT2
    // [.. +256)         stats
    float* ws   = (float*)d_ws;
    float* cnt  = ws;
    float* agg1 = ws + (size_t)n;
    float* bufB = agg1 + (size_t)n * 128;
    float* wT1  = bufB + (size_t)n * 128;
    float* wT2  = wT1 + 32768;
    float* stats = wT2 + 12288;
    float* y2   = agg1;
    float* rbuf = agg1 + (size_t)n * 47;
    float* s1   = bufB;
    float* agg2 = bufB;

    hipMemsetAsync(ws, 0, (size_t)129 * n * sizeof(float), stream);   // cnt + agg1
    hipMemsetAsync(stats, 0, 256 * sizeof(float), stream);

    k_wt<<<(256 * 128 + 128 * 96 + 255) / 256, 256, 0, stream>>>(w1l, w1r, w2l, w2r, wT1, wT2);
    k_scatter1<<<(nE * 32 + 255) / 256, 256, 0, stream>>>(x, ei, agg1, cnt, nE);
    k_gemm1<<<(n + 63) / 64, 256, 0, stream>>>(x, agg1, cnt, wT1, b1l, s1, n);
    k_bn_stats<<<1024, 256, 0, stream>>>(s1, stats, n);
    k_bn_final<<<1, 128, 0, stream>>>(stats, gamma, beta, n);
    k_bn_apply<<<(n * 32 + 255) / 256, 256, 0, stream>>>(s1, stats, n);
    k_gemm2<<<(n + 63) / 64, 256, 0, stream>>>(s1, wT2, y2, rbuf, n);
    hipMemsetAsync(agg2, 0, (size_t)n * 47 * sizeof(float), stream);
    k_scatter2<<<(nE * 12 + 255) / 256, 256, 0, stream>>>(y2, ei, agg2, nE);
    k_final<<<(n + 3) / 4, 256, 0, stream>>>(agg2, rbuf, cnt, b2l, out, n);
}

// Round 2
// 1013.759 us; speedup vs baseline: 2.7345x; 2.7345x over previous
//
#include <hip/hip_runtime.h>
#include <cstdint>

// GNN: 2-layer GraphSAGE (mean aggr, L2-normalize) + BatchNorm(train) + ReLU.
// N=100000 nodes, E=800000 edges, C: 128 -> 128 -> 47.
//
// Round 2: replace atomic scatters with CSR-by-dst + gather.
//  1. k_hist / k_scan_* / k_fill : build CSR (rowStart, srcIdx) once
//  2. k_gather1: aggm[i] = mean_{j in N(i)} x[j]          (no atomics)
//  3. k_gemm1:   s1 = L2norm_rows( aggm @ w1l^T + b1l + x @ w1r^T )
//  4. bn_stats/bn_final/bn_apply: h = relu(BN(s1))
//  5. k_gemm2:   y2 = h @ w2l^T (padded stride 48); rbuf = h @ w2r^T
//               (linear map BEFORE aggregation: 47 ch instead of 128)
//  6. k_gather2_final: out = L2norm( mean_{j} y2[j] + b2l + rbuf )

static __device__ __forceinline__ float warp_sum64(float v) {
    #pragma unroll
    for (int off = 32; off > 0; off >>= 1) v += __shfl_xor(v, off, 64);
    return v;
}

// ---- weight transposes: wT1[k][128] (k<128: w1l, else w1r), wT2[k][96]
__global__ __launch_bounds__(256) void k_wt(
        const float* __restrict__ w1l, const float* __restrict__ w1r,
        const float* __restrict__ w2l, const float* __restrict__ w2r,
        float* __restrict__ wT1, float* __restrict__ wT2) {
    int idx = blockIdx.x * 256 + threadIdx.x;
    if (idx < 256 * 128) {
        int k = idx >> 7, j = idx & 127;
        wT1[idx] = (k < 128) ? w1l[j * 128 + k] : w1r[j * 128 + (k - 128)];
    } else if (idx < 256 * 128 + 128 * 96) {
        int i2 = idx - 256 * 128;
        int k = i2 / 96, j = i2 % 96;
        float v = 0.f;
        if (j < 47)      v = w2l[j * 128 + k];
        else if (j < 94) v = w2r[(j - 47) * 128 + k];
        wT2[i2] = v;
    }
}

// ---- CSR build ----------------------------------------------------------
__global__ __launch_bounds__(256) void k_hist(
        const int* __restrict__ ei, int* __restrict__ deg, int nE) {
    int g = blockIdx.x * 256 + threadIdx.x;
    if (g < nE) atomicAdd(&deg[ei[nE + g]], 1);
}

// per-1024-chunk exclusive starts + chunk totals
__global__ __launch_bounds__(256) void k_scan_blocks(
        const int* __restrict__ deg, int* __restrict__ rowStart,
        int* __restrict__ blockSums, int n) {
    int t = threadIdx.x;
    int base = blockIdx.x * 1024 + t * 4;
    int v[4]; int s = 0;
    #pragma unroll
    for (int u = 0; u < 4; ++u) { v[u] = (base + u < n) ? deg[base + u] : 0; s += v[u]; }
    __shared__ int sh[256];
    sh[t] = s;
    __syncthreads();
    for (int off = 1; off < 256; off <<= 1) {
        int add = (t >= off) ? sh[t - off] : 0;
        __syncthreads();
        sh[t] += add;
        __syncthreads();
    }
    int excl = sh[t] - s;
    #pragma unroll
    for (int u = 0; u < 4; ++u) { if (base + u < n) rowStart[base + u] = excl; excl += v[u]; }
    if (t == 255) blockSums[blockIdx.x] = sh[255];
}

__global__ void k_scan_sums(int* blockSums, int nb) {
    __shared__ int sh[256];
    int t = threadIdx.x;  // 256 threads
    int s = (t < nb) ? blockSums[t] : 0;
    sh[t] = s;
    __syncthreads();
    for (int off = 1; off < 256; off <<= 1) {
        int add = (t >= off) ? sh[t - off] : 0;
        __syncthreads();
        sh[t] += add;
        __syncthreads();
    }
    if (t < nb) blockSums[t] = sh[t] - s;  // exclusive
}

__global__ __launch_bounds__(256) void k_scan_add(
        int* __restrict__ rowStart, const int* __restrict__ blockSums,
        int* __restrict__ cursor, int n) {
    int off = blockSums[blockIdx.x];
    #pragma unroll
    for (int u = 0; u < 4; ++u) {
        int i = blockIdx.x * 1024 + threadIdx.x + u * 256;
        if (i < n) { int r = rowStart[i] + off; rowStart[i] = r; cursor[i] = r; }
    }
}

__global__ __launch_bounds__(256) void k_fill(
        const int* __restrict__ ei, int* __restrict__ cursor,
        int* __restrict__ srcIdx, int nE) {
    int g = blockIdx.x * 256 + threadIdx.x;
    if (g >= nE) return;
    int s = ei[g];
    int d = ei[nE + g];
    int p = atomicAdd(&cursor[d], 1);
    srcIdx[p] = s;
}

// ---- layer-1 gather: 32 lanes/node, lane owns one float4 of 128 channels.
// Writes the MEAN directly (fold 1/max(deg,1)).
__global__ __launch_bounds__(256) void k_gather1(
        const float* __restrict__ x, const int* __restrict__ rowStart,
        const int* __restrict__ deg, const int* __restrict__ srcIdx,
        float* __restrict__ aggm, int n) {
    int t = threadIdx.x;
    int q = t & 31, grp = t >> 5;
    int node = blockIdx.x * 8 + grp;
    if (node >= n) return;
    int beg = rowStart[node], d = deg[node];
    float4 acc = make_float4(0.f, 0.f, 0.f, 0.f);
    for (int e = beg; e < beg + d; ++e) {
        int s = srcIdx[e];
        float4 v = *(const float4*)(x + (size_t)s * 128 + q * 4);
        acc.x += v.x; acc.y += v.y; acc.z += v.z; acc.w += v.w;
    }
    float ic = 1.0f / fmaxf((float)d, 1.0f);
    acc.x *= ic; acc.y *= ic; acc.z *= ic; acc.w *= ic;
    *(float4*)(aggm + (size_t)node * 128 + q * 4) = acc;
}

// ---- GEMM1: 64 rows/block, lane owns (row, 32 channels), K=256.
__global__ __launch_bounds__(256) void k_gemm1(
        const float* __restrict__ x, const float* __restrict__ aggm,
        const float* __restrict__ wT, const float* __restrict__ b1l,
        float* __restrict__ s1, int n) {
    __shared__ float xst[128][64];
    __shared__ float red[4][64];
    int t = threadIdx.x;
    int r = t & 63;
    int cg = t >> 6;
    int j0 = cg * 32;
    int r0 = blockIdx.x * 64;

    float acc[32];
    #pragma unroll
    for (int u = 0; u < 32; ++u) acc[u] = 0.f;

    for (int half = 0; half < 2; ++half) {
        __syncthreads();
        #pragma unroll
        for (int it = 0; it < 8; ++it) {
            int idx = t + it * 256;
            int row = idx >> 5;
            int c4  = idx & 31;
            int gr = r0 + row;
            float4 v = make_float4(0.f, 0.f, 0.f, 0.f);
            if (gr < n) v = *(const float4*)((half == 0 ? aggm : x) + (size_t)gr * 128 + c4 * 4);
            int kb = c4 * 4;
            int sr = (row + c4) & 63;
            xst[kb + 0][sr] = v.x;
            xst[kb + 1][sr] = v.y;
            xst[kb + 2][sr] = v.z;
            xst[kb + 3][sr] = v.w;
        }
        __syncthreads();
        for (int k = 0; k < 128; ++k) {
            float xv = xst[k][(r + (k >> 2)) & 63];
            const float4* wrow = (const float4*)(wT + (size_t)(half * 128 + k) * 128 + j0);
            #pragma unroll
            for (int q = 0; q < 8; ++q) {
                float4 wv = wrow[q];
                acc[q * 4 + 0] = fmaf(xv, wv.x, acc[q * 4 + 0]);
                acc[q * 4 + 1] = fmaf(xv, wv.y, acc[q * 4 + 1]);
                acc[q * 4 + 2] = fmaf(xv, wv.z, acc[q * 4 + 2]);
                acc[q * 4 + 3] = fmaf(xv, wv.w, acc[q * 4 + 3]);
            }
        }
    }

    float partial = 0.f;
    #pragma unroll
    for (int u = 0; u < 32; ++u) {
        acc[u] += b1l[j0 + u];
        partial += acc[u] * acc[u];
    }
    red[cg][r] = partial;
    __syncthreads();
    float nrm2 = red[0][r] + red[1][r] + red[2][r] + red[3][r];
    float inv = 1.0f / fmaxf(sqrtf(nrm2), 1e-12f);
    int gr = r0 + r;
    if (gr < n) {
        float4* out4 = (float4*)(s1 + (size_t)gr * 128 + j0);
        #pragma unroll
        for (int q = 0; q < 8; ++q) {
            float4 o;
            o.x = acc[q * 4 + 0] * inv;
            o.y = acc[q * 4 + 1] * inv;
            o.z = acc[q * 4 + 2] * inv;
            o.w = acc[q * 4 + 3] * inv;
            out4[q] = o;
        }
    }
}

// ---- BN ----------------------------------------------------------------
__global__ __launch_bounds__(256) void k_bn_stats(
        const float* __restrict__ s1, float* __restrict__ stats, int n) {
    int t = threadIdx.x;
    float sv = 0.f, qv = 0.f;
    size_t total = (size_t)n * 128;
    for (size_t i = (size_t)blockIdx.x * 256 + t; i < total; i += (size_t)gridDim.x * 256) {
        float v = s1[i];
        sv += v;
        qv += v * v;
    }
    __shared__ float ls[256], lq[256];
    ls[t] = sv; lq[t] = qv;
    __syncthreads();
    if (t < 128) {
        atomicAdd(&stats[t],       ls[t] + ls[t + 128]);
        atomicAdd(&stats[128 + t], lq[t] + lq[t + 128]);
    }
}

__global__ void k_bn_final(float* stats, const float* __restrict__ gamma,
                           const float* __restrict__ beta, int n) {
    int c = threadIdx.x;  // 128
    float s = stats[c], q = stats[128 + c];
    float fn = (float)n;
    float mean = s / fn;
    float var = q / fn - mean * mean;   // biased variance
    float istd = rsqrtf(var + 1e-5f);
    float a = gamma[c] * istd;
    float b = beta[c] - mean * a;
    stats[c] = a;
    stats[128 + c] = b;
}

__global__ __launch_bounds__(256) void k_bn_apply(
        float* __restrict__ s1, const float* __restrict__ stats, int n) {
    __shared__ float a[128], b[128];
    int t = threadIdx.x;
    if (t < 128) { a[t] = stats[t]; b[t] = stats[128 + t]; }
    __syncthreads();
    int i = blockIdx.x * 256 + t;
    if (i >= n * 32) return;
    float4 v = ((const float4*)s1)[i];
    int c0 = (i & 31) * 4;
    v.x = fmaxf(fmaf(a[c0 + 0], v.x, b[c0 + 0]), 0.f);
    v.y = fmaxf(fmaf(a[c0 + 1], v.y, b[c0 + 1]), 0.f);
    v.z = fmaxf(fmaf(a[c0 + 2], v.z, b[c0 + 2]), 0.f);
    v.w = fmaxf(fmaf(a[c0 + 3], v.w, b[c0 + 3]), 0.f);
    ((float4*)s1)[i] = v;
}

// ---- GEMM2: h[N,128] @ wT2[128][96] -> y2p[N,48] (padded) + rbuf[N,47]
__global__ __launch_bounds__(256) void k_gemm2(
        const float* __restrict__ h, const float* __restrict__ wT2,
        float* __restrict__ y2p, float* __restrict__ rbuf, int n) {
    __shared__ float xst[128][64];
    int t = threadIdx.x;
    int r = t & 63;
    int cg = t >> 6;
    int j0 = cg * 24;
    int r0 = blockIdx.x * 64;

    float acc[24];
    #pragma unroll
    for (int u = 0; u < 24; ++u) acc[u] = 0.f;

    #pragma unroll
    for (int it = 0; it < 8; ++it) {
        int idx = t + it * 256;
        int row = idx >> 5;
        int c4  = idx & 31;
        int gr = r0 + row;
        float4 v = make_float4(0.f, 0.f, 0.f, 0.f);
        if (gr < n) v = *(const float4*)(h + (size_t)gr * 128 + c4 * 4);
        int kb = c4 * 4;
        int sr = (row + c4) & 63;
        xst[kb + 0][sr] = v.x;
        xst[kb + 1][sr] = v.y;
        xst[kb + 2][sr] = v.z;
        xst[kb + 3][sr] = v.w;
    }
    __syncthreads();
    for (int k = 0; k < 128; ++k) {
        float xv = xst[k][(r + (k >> 2)) & 63];
        const float4* wrow = (const float4*)(wT2 + (size_t)k * 96 + j0);
        #pragma unroll
        for (int q = 0; q < 6; ++q) {
            float4 wv = wrow[q];
            acc[q * 4 + 0] = fmaf(xv, wv.x, acc[q * 4 + 0]);
            acc[q * 4 + 1] = fmaf(xv, wv.y, acc[q * 4 + 1]);
            acc[q * 4 + 2] = fmaf(xv, wv.z, acc[q * 4 + 2]);
            acc[q * 4 + 3] = fmaf(xv, wv.w, acc[q * 4 + 3]);
        }
    }
    int gr = r0 + r;
    if (gr >= n) return;
    #pragma unroll
    for (int u = 0; u < 24; ++u) {
        int j = j0 + u;
        if (j < 47)      y2p[(size_t)gr * 48 + j] = acc[u];
        else if (j < 94) rbuf[(size_t)gr * 47 + (j - 47)] = acc[u];
    }
}

// ---- layer-2 gather + combine + L2-norm. One wave per node.
__global__ __launch_bounds__(256) void k_gather2_final(
        const float* __restrict__ y2p, const float* __restrict__ rbuf,
        const int* __restrict__ rowStart, const int* __restrict__ deg,
        const int* __restrict__ srcIdx, const float* __restrict__ b2l,
        float* __restrict__ out, int n) {
    int t = threadIdx.x;
    int lane = t & 63, w = t >> 6;
    int node = blockIdx.x * 4 + w;
    if (node >= n) return;
    float v = 0.f;
    if (lane < 47) {
        int beg = rowStart[node], d = deg[node];
        float acc = 0.f;
        for (int e = beg; e < beg + d; ++e) {
            int s = srcIdx[e];
            acc += y2p[(size_t)s * 48 + lane];
        }
        v = acc / fmaxf((float)d, 1.0f) + b2l[lane] + rbuf[(size_t)node * 47 + lane];
    }
    float ss = warp_sum64(v * v);
    float inv = 1.0f / fmaxf(sqrtf(ss), 1e-12f);
    if (lane < 47) out[(size_t)node * 47 + lane] = v * inv;
}

extern "C" void kernel_launch(void* const* d_in, const int* in_sizes, int n_in,
                              void* d_out, int out_size, void* d_ws, size_t ws_size,
                              hipStream_t stream) {
    const float* x     = (const float*)d_in[0];
    const int*   ei    = (const int*)d_in[1];
    const float* w1l   = (const float*)d_in[2];
    const float* b1l   = (const float*)d_in[3];
    const float* w1r   = (const float*)d_in[4];
    const float* gamma = (const float*)d_in[5];
    const float* beta  = (const float*)d_in[6];
    const float* w2l   = (const float*)d_in[7];
    const float* b2l   = (const float*)d_in[8];
    const float* w2r   = (const float*)d_in[9];
    float* out = (float*)d_out;

    int n  = in_sizes[0] / 128;   // 100000
    int nE = in_sizes[1] / 2;     // 800000

    // ---- workspace layout ----
    // ints:   deg[n] | rowStart[n] | cursor[n] | srcIdx[nE] | blockSums[256]
    // floats: aggm[128n] (reused: y2p[48n] + rbuf[47n]) | s1[128n]
    //         | wT1[32768] | wT2[12288] | stats[256]
    int* deg       = (int*)d_ws;
    int* rowStart  = deg + n;
    int* cursor    = rowStart + n;
    int* srcIdx    = cursor + n;
    int* blockSums = srcIdx + nE;
    float* aggm = (float*)(blockSums + 256);
    float* s1   = aggm + (size_t)n * 128;
    float* wT1  = s1 + (size_t)n * 128;
    float* wT2  = wT1 + 32768;
    float* stats = wT2 + 12288;
    float* y2p  = aggm;                       // stride 48 (after aggm is dead)
    float* rbuf = aggm + (size_t)n * 48;

    int nChunks = (n + 1023) / 1024;          // 98

    hipMemsetAsync(deg, 0, (size_t)n * sizeof(int), stream);
    hipMemsetAsync(stats, 0, 256 * sizeof(float), stream);

    k_wt<<<(256 * 128 + 128 * 96 + 255) / 256, 256, 0, stream>>>(w1l, w1r, w2l, w2r, wT1, wT2);
    // CSR build
    k_hist<<<(nE + 255) / 256, 256, 0, stream>>>(ei, deg, nE);
    k_scan_blocks<<<nChunks, 256, 0, stream>>>(deg, rowStart, blockSums, n);
    k_scan_sums<<<1, 256, 0, stream>>>(blockSums, nChunks);
    k_scan_add<<<nChunks, 256, 0, stream>>>(rowStart, blockSums, cursor, n);
    k_fill<<<(nE + 255) / 256, 256, 0, stream>>>(ei, cursor, srcIdx, nE);
    // layer 1
    k_gather1<<<(n + 7) / 8, 256, 0, stream>>>(x, rowStart, deg, srcIdx, aggm, n);
    k_gemm1<<<(n + 63) / 64, 256, 0, stream>>>(x, aggm, wT1, b1l, s1, n);
    k_bn_stats<<<1024, 256, 0, stream>>>(s1, stats, n);
    k_bn_final<<<1, 128, 0, stream>>>(stats, gamma, beta, n);
    k_bn_apply<<<(n * 32 + 255) / 256, 256, 0, stream>>>(s1, stats, n);
    // layer 2
    k_gemm2<<<(n + 63) / 64, 256, 0, stream>>>(s1, wT2, y2p, rbuf, n);
    k_gather2_final<<<(n + 3) / 4, 256, 0, stream>>>(y2p, rbuf, rowStart, deg, srcIdx, b2l, out, n);
}

// Round 3
// 570.792 us; speedup vs baseline: 4.8567x; 1.7761x over previous
//
#include <hip/hip_runtime.h>
#include <cstdint>

// GNN: 2-layer GraphSAGE (mean aggr, L2-normalize) + BatchNorm(train) + ReLU.
// N=100000 nodes, E=800000 edges, C: 128 -> 128 -> 47.
//
// Round 3: register-blocked fp32 GEMMs (8x8 microtile/thread, 128x128 block,
// K-tiles of 32 staged in LDS for BOTH x and weights). R2's gemm kernels
// re-fetched weights from global every k-step -> vmem-issue bound (VALUBusy
// 13%). Now per k-step: 4 ds_read_b128 + 64 VALU FMA -> VALU-dominant.

static __device__ __forceinline__ float warp_sum64(float v) {
    #pragma unroll
    for (int off = 32; off > 0; off >>= 1) v += __shfl_xor(v, off, 64);
    return v;
}

// ---- weight transposes: wT1[k][128] (k<128: w1l, else w1r),
// ---- wT2p[k][128] (j<47: w2l, j<94: w2r, else 0)
__global__ __launch_bounds__(256) void k_wt(
        const float* __restrict__ w1l, const float* __restrict__ w1r,
        const float* __restrict__ w2l, const float* __restrict__ w2r,
        float* __restrict__ wT1, float* __restrict__ wT2p) {
    int idx = blockIdx.x * 256 + threadIdx.x;
    if (idx < 256 * 128) {
        int k = idx >> 7, j = idx & 127;
        wT1[idx] = (k < 128) ? w1l[j * 128 + k] : w1r[j * 128 + (k - 128)];
    } else if (idx < 256 * 128 + 128 * 128) {
        int i2 = idx - 256 * 128;
        int k = i2 >> 7, j = i2 & 127;
        float v = 0.f;
        if (j < 47)      v = w2l[j * 128 + k];
        else if (j < 94) v = w2r[(j - 47) * 128 + k];
        wT2p[i2] = v;
    }
}

// ---- CSR build ----------------------------------------------------------
__global__ __launch_bounds__(256) void k_hist(
        const int* __restrict__ ei, int* __restrict__ deg, int nE) {
    int g = blockIdx.x * 256 + threadIdx.x;
    if (g < nE) atomicAdd(&deg[ei[nE + g]], 1);
}

__global__ __launch_bounds__(256) void k_scan_blocks(
        const int* __restrict__ deg, int* __restrict__ rowStart,
        int* __restrict__ blockSums, int n) {
    int t = threadIdx.x;
    int base = blockIdx.x * 1024 + t * 4;
    int v[4]; int s = 0;
    #pragma unroll
    for (int u = 0; u < 4; ++u) { v[u] = (base + u < n) ? deg[base + u] : 0; s += v[u]; }
    __shared__ int sh[256];
    sh[t] = s;
    __syncthreads();
    for (int off = 1; off < 256; off <<= 1) {
        int add = (t >= off) ? sh[t - off] : 0;
        __syncthreads();
        sh[t] += add;
        __syncthreads();
    }
    int excl = sh[t] - s;
    #pragma unroll
    for (int u = 0; u < 4; ++u) { if (base + u < n) rowStart[base + u] = excl; excl += v[u]; }
    if (t == 255) blockSums[blockIdx.x] = sh[255];
}

__global__ void k_scan_sums(int* blockSums, int nb) {
    __shared__ int sh[256];
    int t = threadIdx.x;
    int s = (t < nb) ? blockSums[t] : 0;
    sh[t] = s;
    __syncthreads();
    for (int off = 1; off < 256; off <<= 1) {
        int add = (t >= off) ? sh[t - off] : 0;
        __syncthreads();
        sh[t] += add;
        __syncthreads();
    }
    if (t < nb) blockSums[t] = sh[t] - s;  // exclusive
}

__global__ __launch_bounds__(256) void k_scan_add(
        int* __restrict__ rowStart, const int* __restrict__ blockSums,
        int* __restrict__ cursor, int n) {
    int off = blockSums[blockIdx.x];
    #pragma unroll
    for (int u = 0; u < 4; ++u) {
        int i = blockIdx.x * 1024 + threadIdx.x + u * 256;
        if (i < n) { int r = rowStart[i] + off; rowStart[i] = r; cursor[i] = r; }
    }
}

__global__ __launch_bounds__(256) void k_fill(
        const int* __restrict__ ei, int* __restrict__ cursor,
        int* __restrict__ srcIdx, int nE) {
    int g = blockIdx.x * 256 + threadIdx.x;
    if (g >= nE) return;
    int s = ei[g];
    int d = ei[nE + g];
    int p = atomicAdd(&cursor[d], 1);
    srcIdx[p] = s;
}

// ---- layer-1 gather: 32 lanes/node, lane owns one float4 of 128 channels.
__global__ __launch_bounds__(256) void k_gather1(
        const float* __restrict__ x, const int* __restrict__ rowStart,
        const int* __restrict__ deg, const int* __restrict__ srcIdx,
        float* __restrict__ aggm, int n) {
    int t = threadIdx.x;
    int q = t & 31, grp = t >> 5;
    int node = blockIdx.x * 8 + grp;
    if (node >= n) return;
    int beg = rowStart[node], d = deg[node];
    float4 acc = make_float4(0.f, 0.f, 0.f, 0.f);
    for (int e = beg; e < beg + d; ++e) {
        int s = srcIdx[e];
        float4 v = *(const float4*)(x + (size_t)s * 128 + q * 4);
        acc.x += v.x; acc.y += v.y; acc.z += v.z; acc.w += v.w;
    }
    float ic = 1.0f / fmaxf((float)d, 1.0f);
    acc.x *= ic; acc.y *= ic; acc.z *= ic; acc.w *= ic;
    *(float4*)(aggm + (size_t)node * 128 + q * 4) = acc;
}

// ---- GEMM1: block = 128 rows x 128 cols, thread = 8x8, K=256 in 8 tiles.
// s1 = L2norm_rows( aggm @ w1l^T + b1l + x @ w1r^T )
__global__ __launch_bounds__(256, 2) void k_gemm1(
        const float* __restrict__ x, const float* __restrict__ aggm,
        const float* __restrict__ wT, const float* __restrict__ b1l,
        float* __restrict__ s1, int n) {
    __shared__ float xs[32][128];   // [k][row]
    __shared__ float ws[32][132];   // [k][j], padded
    int t = threadIdx.x;
    int tx = t & 15, ty = t >> 4;   // tx: j-octet, ty: row-octet
    int r0 = blockIdx.x * 128;

    float acc[8][8];
    #pragma unroll
    for (int a = 0; a < 8; ++a)
        #pragma unroll
        for (int b = 0; b < 8; ++b) acc[a][b] = 0.f;

    for (int kt = 0; kt < 8; ++kt) {
        const float* src = (kt < 4) ? aggm : x;
        int kbase = (kt & 3) * 32;
        __syncthreads();
        // stage x-tile: 128 rows x 32 k (transposed into xs)
        #pragma unroll
        for (int it = 0; it < 4; ++it) {
            int i = t + it * 256;           // 0..1023
            int row = i >> 3, c4 = i & 7;
            int gr = r0 + row;
            float4 v = make_float4(0.f, 0.f, 0.f, 0.f);
            if (gr < n) v = *(const float4*)(src + (size_t)gr * 128 + kbase + c4 * 4);
            xs[c4 * 4 + 0][row] = v.x;
            xs[c4 * 4 + 1][row] = v.y;
            xs[c4 * 4 + 2][row] = v.z;
            xs[c4 * 4 + 3][row] = v.w;
        }
        // stage w-tile: 32 k x 128 j
        #pragma unroll
        for (int it = 0; it < 4; ++it) {
            int i = t + it * 256;
            int krow = i >> 5, jc = i & 31;
            float4 wv = *(const float4*)(wT + (size_t)(kt * 32 + krow) * 128 + jc * 4);
            *(float4*)&ws[krow][jc * 4] = wv;
        }
        __syncthreads();
        #pragma unroll 4
        for (int k = 0; k < 32; ++k) {
            float4 xa = *(const float4*)&xs[k][ty * 8];
            float4 xb = *(const float4*)&xs[k][ty * 8 + 4];
            float4 wa = *(const float4*)&ws[k][tx * 8];
            float4 wb = *(const float4*)&ws[k][tx * 8 + 4];
            float xr[8] = {xa.x, xa.y, xa.z, xa.w, xb.x, xb.y, xb.z, xb.w};
            float wj[8] = {wa.x, wa.y, wa.z, wa.w, wb.x, wb.y, wb.z, wb.w};
            #pragma unroll
            for (int a = 0; a < 8; ++a)
                #pragma unroll
                for (int b = 0; b < 8; ++b)
                    acc[a][b] = fmaf(xr[a], wj[b], acc[a][b]);
        }
    }

    // epilogue: bias, then row L2-norm via LDS reduction (reuse xs as red)
    float bj[8];
    #pragma unroll
    for (int b = 0; b < 8; ++b) bj[b] = b1l[tx * 8 + b];
    #pragma unroll
    for (int a = 0; a < 8; ++a)
        #pragma unroll
        for (int b = 0; b < 8; ++b) acc[a][b] += bj[b];

    __syncthreads();
    float* red = &xs[0][0];          // red[row*17 + tx], 128*17 floats
    #pragma unroll
    for (int a = 0; a < 8; ++a) {
        float p = 0.f;
        #pragma unroll
        for (int b = 0; b < 8; ++b) p += acc[a][b] * acc[a][b];
        red[(ty * 8 + a) * 17 + tx] = p;
    }
    __syncthreads();
    float* invn = &ws[0][0];         // invn[128]
    if (t < 128) {
        float s = 0.f;
        #pragma unroll
        for (int i = 0; i < 16; ++i) s += red[t * 17 + i];
        invn[t] = 1.0f / fmaxf(sqrtf(s), 1e-12f);
    }
    __syncthreads();
    #pragma unroll
    for (int a = 0; a < 8; ++a) {
        int row = ty * 8 + a;
        int gr = r0 + row;
        if (gr < n) {
            float iv = invn[row];
            float4 o1 = make_float4(acc[a][0] * iv, acc[a][1] * iv, acc[a][2] * iv, acc[a][3] * iv);
            float4 o2 = make_float4(acc[a][4] * iv, acc[a][5] * iv, acc[a][6] * iv, acc[a][7] * iv);
            float4* dst = (float4*)(s1 + (size_t)gr * 128 + tx * 8);
            dst[0] = o1;
            dst[1] = o2;
        }
    }
}

// ---- BN ----------------------------------------------------------------
__global__ __launch_bounds__(256) void k_bn_stats(
        const float* __restrict__ s1, float* __restrict__ stats, int n) {
    int t = threadIdx.x;
    float sv = 0.f, qv = 0.f;
    size_t total = (size_t)n * 128;
    for (size_t i = (size_t)blockIdx.x * 256 + t; i < total; i += (size_t)gridDim.x * 256) {
        float v = s1[i];
        sv += v;
        qv += v * v;
    }
    __shared__ float ls[256], lq[256];
    ls[t] = sv; lq[t] = qv;
    __syncthreads();
    if (t < 128) {
        atomicAdd(&stats[t],       ls[t] + ls[t + 128]);
        atomicAdd(&stats[128 + t], lq[t] + lq[t + 128]);
    }
}

__global__ void k_bn_final(float* stats, const float* __restrict__ gamma,
                           const float* __restrict__ beta, int n) {
    int c = threadIdx.x;  // 128
    float s = stats[c], q = stats[128 + c];
    float fn = (float)n;
    float mean = s / fn;
    float var = q / fn - mean * mean;   // biased variance
    float istd = rsqrtf(var + 1e-5f);
    float a = gamma[c] * istd;
    float b = beta[c] - mean * a;
    stats[c] = a;
    stats[128 + c] = b;
}

__global__ __launch_bounds__(256) void k_bn_apply(
        float* __restrict__ s1, const float* __restrict__ stats, int n) {
    __shared__ float a[128], b[128];
    int t = threadIdx.x;
    if (t < 128) { a[t] = stats[t]; b[t] = stats[128 + t]; }
    __syncthreads();
    int i = blockIdx.x * 256 + t;
    if (i >= n * 32) return;
    float4 v = ((const float4*)s1)[i];
    int c0 = (i & 31) * 4;
    v.x = fmaxf(fmaf(a[c0 + 0], v.x, b[c0 + 0]), 0.f);
    v.y = fmaxf(fmaf(a[c0 + 1], v.y, b[c0 + 1]), 0.f);
    v.z = fmaxf(fmaf(a[c0 + 2], v.z, b[c0 + 2]), 0.f);
    v.w = fmaxf(fmaf(a[c0 + 3], v.w, b[c0 + 3]), 0.f);
    ((float4*)s1)[i] = v;
}

// ---- GEMM2: h[N,128] @ wT2p[128][128] -> y2p[N,48] (j<47) + rbuf[N,47]
__global__ __launch_bounds__(256, 2) void k_gemm2(
        const float* __restrict__ h, const float* __restrict__ wT2p,
        float* __restrict__ y2p, float* __restrict__ rbuf, int n) {
    __shared__ float xs[32][128];
    __shared__ float ws[32][132];
    int t = threadIdx.x;
    int tx = t & 15, ty = t >> 4;
    int r0 = blockIdx.x * 128;

    float acc[8][8];
    #pragma unroll
    for (int a = 0; a < 8; ++a)
        #pragma unroll
        for (int b = 0; b < 8; ++b) acc[a][b] = 0.f;

    for (int kt = 0; kt < 4; ++kt) {
        int kbase = kt * 32;
        __syncthreads();
        #pragma unroll
        for (int it = 0; it < 4; ++it) {
            int i = t + it * 256;
            int row = i >> 3, c4 = i & 7;
            int gr = r0 + row;
            float4 v = make_float4(0.f, 0.f, 0.f, 0.f);
            if (gr < n) v = *(const float4*)(h + (size_t)gr * 128 + kbase + c4 * 4);
            xs[c4 * 4 + 0][row] = v.x;
            xs[c4 * 4 + 1][row] = v.y;
            xs[c4 * 4 + 2][row] = v.z;
            xs[c4 * 4 + 3][row] = v.w;
        }
        #pragma unroll
        for (int it = 0; it < 4; ++it) {
            int i = t + it * 256;
            int krow = i >> 5, jc = i & 31;
            float4 wv = *(const float4*)(wT2p + (size_t)(kbase + krow) * 128 + jc * 4);
            *(float4*)&ws[krow][jc * 4] = wv;
        }
        __syncthreads();
        #pragma unroll 4
        for (int k = 0; k < 32; ++k) {
            float4 xa = *(const float4*)&xs[k][ty * 8];
            float4 xb = *(const float4*)&xs[k][ty * 8 + 4];
            float4 wa = *(const float4*)&ws[k][tx * 8];
            float4 wb = *(const float4*)&ws[k][tx * 8 + 4];
            float xr[8] = {xa.x, xa.y, xa.z, xa.w, xb.x, xb.y, xb.z, xb.w};
            float wj[8] = {wa.x, wa.y, wa.z, wa.w, wb.x, wb.y, wb.z, wb.w};
            #pragma unroll
            for (int a = 0; a < 8; ++a)
                #pragma unroll
                for (int b = 0; b < 8; ++b)
                    acc[a][b] = fmaf(xr[a], wj[b], acc[a][b]);
        }
    }

    #pragma unroll
    for (int a = 0; a < 8; ++a) {
        int gr = r0 + ty * 8 + a;
        if (gr >= n) continue;
        #pragma unroll
        for (int b = 0; b < 8; ++b) {
            int j = tx * 8 + b;
            if (j < 47)      y2p[(size_t)gr * 48 + j] = acc[a][b];
            else if (j < 94) rbuf[(size_t)gr * 47 + (j - 47)] = acc[a][b];
        }
    }
}

// ---- layer-2 gather + combine + L2-norm. One wave per node.
__global__ __launch_bounds__(256) void k_gather2_final(
        const float* __restrict__ y2p, const float* __restrict__ rbuf,
        const int* __restrict__ rowStart, const int* __restrict__ deg,
        const int* __restrict__ srcIdx, const float* __restrict__ b2l,
        float* __restrict__ out, int n) {
    int t = threadIdx.x;
    int lane = t & 63, w = t >> 6;
    int node = blockIdx.x * 4 + w;
    if (node >= n) return;
    float v = 0.f;
    if (lane < 47) {
        int beg = rowStart[node], d = deg[node];
        float acc = 0.f;
        for (int e = beg; e < beg + d; ++e) {
            int s = srcIdx[e];
            acc += y2p[(size_t)s * 48 + lane];
        }
        v = acc / fmaxf((float)d, 1.0f) + b2l[lane] + rbuf[(size_t)node * 47 + lane];
    }
    float ss = warp_sum64(v * v);
    float inv = 1.0f / fmaxf(sqrtf(ss), 1e-12f);
    if (lane < 47) out[(size_t)node * 47 + lane] = v * inv;
}

extern "C" void kernel_launch(void* const* d_in, const int* in_sizes, int n_in,
                              void* d_out, int out_size, void* d_ws, size_t ws_size,
                              hipStream_t stream) {
    const float* x     = (const float*)d_in[0];
    const int*   ei    = (const int*)d_in[1];
    const float* w1l   = (const float*)d_in[2];
    const float* b1l   = (const float*)d_in[3];
    const float* w1r   = (const float*)d_in[4];
    const float* gamma = (const float*)d_in[5];
    const float* beta  = (const float*)d_in[6];
    const float* w2l   = (const float*)d_in[7];
    const float* b2l   = (const float*)d_in[8];
    const float* w2r   = (const float*)d_in[9];
    float* out = (float*)d_out;

    int n  = in_sizes[0] / 128;   // 100000
    int nE = in_sizes[1] / 2;     // 800000

    // ---- workspace layout ----
    // ints:   deg[n] | rowStart[n] | cursor[n] | srcIdx[nE] | blockSums[256]
    // floats: aggm[128n] (reused: y2p[48n] + rbuf[47n]) | s1[128n]
    //         | wT1[32768] | wT2p[16384] | stats[256]
    int* deg       = (int*)d_ws;
    int* rowStart  = deg + n;
    int* cursor    = rowStart + n;
    int* srcIdx    = cursor + n;
    int* blockSums = srcIdx + nE;
    float* aggm = (float*)(blockSums + 256);
    float* s1   = aggm + (size_t)n * 128;
    float* wT1  = s1 + (size_t)n * 128;
    float* wT2p = wT1 + 32768;
    float* stats = wT2p + 16384;
    float* y2p  = aggm;                       // stride 48 (aggm dead by then)
    float* rbuf = aggm + (size_t)n * 48;

    int nChunks = (n + 1023) / 1024;          // 98

    hipMemsetAsync(deg, 0, (size_t)n * sizeof(int), stream);
    hipMemsetAsync(stats, 0, 256 * sizeof(float), stream);

    k_wt<<<(256 * 128 + 128 * 128 + 255) / 256, 256, 0, stream>>>(w1l, w1r, w2l, w2r, wT1, wT2p);
    // CSR build
    k_hist<<<(nE + 255) / 256, 256, 0, stream>>>(ei, deg, nE);
    k_scan_blocks<<<nChunks, 256, 0, stream>>>(deg, rowStart, blockSums, n);
    k_scan_sums<<<1, 256, 0, stream>>>(blockSums, nChunks);
    k_scan_add<<<nChunks, 256, 0, stream>>>(rowStart, blockSums, cursor, n);
    k_fill<<<(nE + 255) / 256, 256, 0, stream>>>(ei, cursor, srcIdx, nE);
    // layer 1
    k_gather1<<<(n + 7) / 8, 256, 0, stream>>>(x, rowStart, deg, srcIdx, aggm, n);
    k_gemm1<<<(n + 127) / 128, 256, 0, stream>>>(x, aggm, wT1, b1l, s1, n);
    k_bn_stats<<<1024, 256, 0, stream>>>(s1, stats, n);
    k_bn_final<<<1, 128, 0, stream>>>(stats, gamma, beta, n);
    k_bn_apply<<<(n * 32 + 255) / 256, 256, 0, stream>>>(s1, stats, n);
    // layer 2
    k_gemm2<<<(n + 127) / 128, 256, 0, stream>>>(s1, wT2p, y2p, rbuf, n);
    k_gather2_final<<<(n + 3) / 4, 256, 0, stream>>>(y2p, rbuf, rowStart, deg, srcIdx, b2l, out, n);
}

// Round 4
// 544.342 us; speedup vs baseline: 5.0926x; 1.0486x over previous
//
#include <hip/hip_runtime.h>
#include <cstdint>

// GNN: 2-layer GraphSAGE (mean aggr, L2-normalize) + BatchNorm(train) + ReLU.
// N=100000 nodes, E=800000 edges, C: 128 -> 128 -> 47.
//
// Round 4:
//  - gemm microtile remapped to split-tiles (cols tx*4 & 64+tx*4, rows ty*4 &
//    64+ty*4): ws b128 reads go 4-way-conflict -> 2-way (free); stride 132.
//  - register prefetch of next k-tile issued before compute (hide global lat).
//  - __launch_bounds__(256,4): 4 blocks/CU (was 2).
//  - BN fused: stats accumulated in gemm1 epilogue (atomics per block);
//    BN+relu applied in gemm2 staging. k_bn_stats / k_bn_apply deleted.
//  - b2l folded into rbuf in gemm2 epilogue.

static __device__ __forceinline__ float warp_sum64(float v) {
    #pragma unroll
    for (int off = 32; off > 0; off >>= 1) v += __shfl_xor(v, off, 64);
    return v;
}

// ---- weight transposes: wT1[k][128] (k<128: w1l, else w1r),
// ---- wT2p[k][128] (j<47: w2l, j<94: w2r, else 0)
__global__ __launch_bounds__(256) void k_wt(
        const float* __restrict__ w1l, const float* __restrict__ w1r,
        const float* __restrict__ w2l, const float* __restrict__ w2r,
        float* __restrict__ wT1, float* __restrict__ wT2p) {
    int idx = blockIdx.x * 256 + threadIdx.x;
    if (idx < 256 * 128) {
        int k = idx >> 7, j = idx & 127;
        wT1[idx] = (k < 128) ? w1l[j * 128 + k] : w1r[j * 128 + (k - 128)];
    } else if (idx < 256 * 128 + 128 * 128) {
        int i2 = idx - 256 * 128;
        int k = i2 >> 7, j = i2 & 127;
        float v = 0.f;
        if (j < 47)      v = w2l[j * 128 + k];
        else if (j < 94) v = w2r[(j - 47) * 128 + k];
        wT2p[i2] = v;
    }
}

// ---- CSR build ----------------------------------------------------------
__global__ __launch_bounds__(256) void k_hist(
        const int* __restrict__ ei, int* __restrict__ deg, int nE) {
    int g = blockIdx.x * 256 + threadIdx.x;
    if (g < nE) atomicAdd(&deg[ei[nE + g]], 1);
}

__global__ __launch_bounds__(256) void k_scan_blocks(
        const int* __restrict__ deg, int* __restrict__ rowStart,
        int* __restrict__ blockSums, int n) {
    int t = threadIdx.x;
    int base = blockIdx.x * 1024 + t * 4;
    int v[4]; int s = 0;
    #pragma unroll
    for (int u = 0; u < 4; ++u) { v[u] = (base + u < n) ? deg[base + u] : 0; s += v[u]; }
    __shared__ int sh[256];
    sh[t] = s;
    __syncthreads();
    for (int off = 1; off < 256; off <<= 1) {
        int add = (t >= off) ? sh[t - off] : 0;
        __syncthreads();
        sh[t] += add;
        __syncthreads();
    }
    int excl = sh[t] - s;
    #pragma unroll
    for (int u = 0; u < 4; ++u) { if (base + u < n) rowStart[base + u] = excl; excl += v[u]; }
    if (t == 255) blockSums[blockIdx.x] = sh[255];
}

__global__ void k_scan_sums(int* blockSums, int nb) {
    __shared__ int sh[256];
    int t = threadIdx.x;
    int s = (t < nb) ? blockSums[t] : 0;
    sh[t] = s;
    __syncthreads();
    for (int off = 1; off < 256; off <<= 1) {
        int add = (t >= off) ? sh[t - off] : 0;
        __syncthreads();
        sh[t] += add;
        __syncthreads();
    }
    if (t < nb) blockSums[t] = sh[t] - s;  // exclusive
}

__global__ __launch_bounds__(256) void k_scan_add(
        int* __restrict__ rowStart, const int* __restrict__ blockSums,
        int* __restrict__ cursor, int n) {
    int off = blockSums[blockIdx.x];
    #pragma unroll
    for (int u = 0; u < 4; ++u) {
        int i = blockIdx.x * 1024 + threadIdx.x + u * 256;
        if (i < n) { int r = rowStart[i] + off; rowStart[i] = r; cursor[i] = r; }
    }
}

__global__ __launch_bounds__(256) void k_fill(
        const int* __restrict__ ei, int* __restrict__ cursor,
        int* __restrict__ srcIdx, int nE) {
    int g = blockIdx.x * 256 + threadIdx.x;
    if (g >= nE) return;
    int s = ei[g];
    int d = ei[nE + g];
    int p = atomicAdd(&cursor[d], 1);
    srcIdx[p] = s;
}

// ---- layer-1 gather: 32 lanes/node, lane owns one float4 of 128 channels.
__global__ __launch_bounds__(256) void k_gather1(
        const float* __restrict__ x, const int* __restrict__ rowStart,
        const int* __restrict__ deg, const int* __restrict__ srcIdx,
        float* __restrict__ aggm, int n) {
    int t = threadIdx.x;
    int q = t & 31, grp = t >> 5;
    int node = blockIdx.x * 8 + grp;
    if (node >= n) return;
    int beg = rowStart[node], d = deg[node];
    float4 acc = make_float4(0.f, 0.f, 0.f, 0.f);
    for (int e = beg; e < beg + d; ++e) {
        int s = srcIdx[e];
        float4 v = *(const float4*)(x + (size_t)s * 128 + q * 4);
        acc.x += v.x; acc.y += v.y; acc.z += v.z; acc.w += v.w;
    }
    float ic = 1.0f / fmaxf((float)d, 1.0f);
    acc.x *= ic; acc.y *= ic; acc.z *= ic; acc.w *= ic;
    *(float4*)(aggm + (size_t)node * 128 + q * 4) = acc;
}

// ---- GEMM1: 128x128 block, split 8x8 microtile, K=256 (aggm then x halves).
// s1 = L2norm_rows( aggm @ w1l^T + b1l + x @ w1r^T ); also accumulates
// per-channel sum/sumsq of s1 into stats[0:128]/stats[128:256] (atomics).
__global__ __launch_bounds__(256, 4) void k_gemm1(
        const float* __restrict__ x, const float* __restrict__ aggm,
        const float* __restrict__ wT, const float* __restrict__ b1l,
        float* __restrict__ s1, float* __restrict__ stats, int n) {
    __shared__ float xs[32 * 132];   // [k][row], stride 132
    __shared__ float ws[32 * 132];   // [k][j],   stride 132
    int t = threadIdx.x;
    int tx = t & 15, ty = t >> 4;
    int r0 = blockIdx.x * 128;

    int srow = t >> 3, sc4 = t & 7;     // x-tile staging: row base, float4 idx
    int wrow = t >> 5, wjc = t & 31;    // w-tile staging

    float4 xv[4], wv[4];
    // prefetch tile 0 (aggm, kbase 0)
    #pragma unroll
    for (int it = 0; it < 4; ++it) {
        int gr = r0 + srow + it * 32;
        xv[it] = (gr < n) ? *(const float4*)(aggm + (size_t)gr * 128 + sc4 * 4)
                          : make_float4(0.f, 0.f, 0.f, 0.f);
        wv[it] = *(const float4*)(wT + (size_t)(wrow + it * 8) * 128 + wjc * 4);
    }

    float acc[8][8] = {};

    for (int kt = 0; kt < 8; ++kt) {
        __syncthreads();
        #pragma unroll
        for (int it = 0; it < 4; ++it) {
            int row = srow + it * 32;
            xs[(sc4 * 4 + 0) * 132 + row] = xv[it].x;
            xs[(sc4 * 4 + 1) * 132 + row] = xv[it].y;
            xs[(sc4 * 4 + 2) * 132 + row] = xv[it].z;
            xs[(sc4 * 4 + 3) * 132 + row] = xv[it].w;
            *(float4*)&ws[(wrow + it * 8) * 132 + wjc * 4] = wv[it];
        }
        __syncthreads();
        if (kt < 7) {
            int k1 = kt + 1;
            const float* src = (k1 < 4) ? aggm : x;
            int kbase = (k1 & 3) * 32;
            #pragma unroll
            for (int it = 0; it < 4; ++it) {
                int gr = r0 + srow + it * 32;
                xv[it] = (gr < n) ? *(const float4*)(src + (size_t)gr * 128 + kbase + sc4 * 4)
                                  : make_float4(0.f, 0.f, 0.f, 0.f);
                wv[it] = *(const float4*)(wT + (size_t)(k1 * 32 + wrow + it * 8) * 128 + wjc * 4);
            }
        }
        #pragma unroll 4
        for (int k = 0; k < 32; ++k) {
            float4 x0 = *(const float4*)&xs[k * 132 + ty * 4];
            float4 x1 = *(const float4*)&xs[k * 132 + 64 + ty * 4];
            float4 w0 = *(const float4*)&ws[k * 132 + tx * 4];
            float4 w1 = *(const float4*)&ws[k * 132 + 64 + tx * 4];
            float xr[8] = {x0.x, x0.y, x0.z, x0.w, x1.x, x1.y, x1.z, x1.w};
            float wj[8] = {w0.x, w0.y, w0.z, w0.w, w1.x, w1.y, w1.z, w1.w};
            #pragma unroll
            for (int a = 0; a < 8; ++a)
                #pragma unroll
                for (int b = 0; b < 8; ++b)
                    acc[a][b] = fmaf(xr[a], wj[b], acc[a][b]);
        }
    }

    // epilogue: bias, row L2-norm, store, per-channel stats partials
    #pragma unroll
    for (int b = 0; b < 8; ++b) {
        int j = (b < 4) ? tx * 4 + b : 64 + tx * 4 + (b - 4);
        float bj = b1l[j];
        #pragma unroll
        for (int a = 0; a < 8; ++a) acc[a][b] += bj;
    }

    __syncthreads();   // LDS tiles free
    #pragma unroll
    for (int a = 0; a < 8; ++a) {
        int row = (a < 4) ? ty * 4 + a : 64 + ty * 4 + (a - 4);
        float p = 0.f;
        #pragma unroll
        for (int b = 0; b < 8; ++b) p += acc[a][b] * acc[a][b];
        xs[row * 17 + tx] = p;
    }
    __syncthreads();
    if (t < 128) {
        float s = 0.f;
        #pragma unroll
        for (int i = 0; i < 16; ++i) s += xs[t * 17 + i];
        ws[t] = 1.0f / fmaxf(sqrtf(s), 1e-12f);
    }
    __syncthreads();
    float colS[8] = {}, colQ[8] = {};
    #pragma unroll
    for (int a = 0; a < 8; ++a) {
        int row = (a < 4) ? ty * 4 + a : 64 + ty * 4 + (a - 4);
        int gr = r0 + row;
        if (gr >= n) continue;
        float iv = ws[row];
        float v[8];
        #pragma unroll
        for (int b = 0; b < 8; ++b) {
            v[b] = acc[a][b] * iv;
            colS[b] += v[b];
            colQ[b] += v[b] * v[b];
        }
        *(float4*)(s1 + (size_t)gr * 128 + tx * 4)      = make_float4(v[0], v[1], v[2], v[3]);
        *(float4*)(s1 + (size_t)gr * 128 + 64 + tx * 4) = make_float4(v[4], v[5], v[6], v[7]);
    }
    __syncthreads();   // invn + red consumed
    #pragma unroll
    for (int b = 0; b < 8; ++b) {
        int j = (b < 4) ? tx * 4 + b : 64 + tx * 4 + (b - 4);
        xs[j * 17 + ty] = colS[b];
        ws[j * 17 + ty] = colQ[b];
    }
    __syncthreads();
    if (t < 128) {
        float s = 0.f, q = 0.f;
        #pragma unroll
        for (int i = 0; i < 16; ++i) { s += xs[t * 17 + i]; q += ws[t * 17 + i]; }
        atomicAdd(&stats[t], s);
        atomicAdd(&stats[128 + t], q);
    }
}

// ---- BN coefficient finalize: stats -> (a, b) per channel
__global__ void k_bn_final(float* stats, const float* __restrict__ gamma,
                           const float* __restrict__ beta, int n) {
    int c = threadIdx.x;  // 128
    float s = stats[c], q = stats[128 + c];
    float fn = (float)n;
    float mean = s / fn;
    float var = q / fn - mean * mean;   // biased variance
    float istd = rsqrtf(var + 1e-5f);
    float a = gamma[c] * istd;
    float b = beta[c] - mean * a;
    stats[c] = a;
    stats[128 + c] = b;
}

// ---- GEMM2: relu(BN(s1)) @ wT2p[128][128] -> y2p[N,48] (j<47) +
//      rbuf[N,47] (j in 47..93, with b2l folded). BN+relu applied at staging.
__global__ __launch_bounds__(256, 4) void k_gemm2(
        const float* __restrict__ s1, const float* __restrict__ wT2p,
        const float* __restrict__ stats, const float* __restrict__ b2l,
        float* __restrict__ y2p, float* __restrict__ rbuf, int n) {
    __shared__ float xs[32 * 132];
    __shared__ float ws[32 * 132];
    int t = threadIdx.x;
    int tx = t & 15, ty = t >> 4;
    int r0 = blockIdx.x * 128;

    int srow = t >> 3, sc4 = t & 7;
    int wrow = t >> 5, wjc = t & 31;

    float4 xv[4], wv[4];
    #pragma unroll
    for (int it = 0; it < 4; ++it) {
        int gr = r0 + srow + it * 32;
        int c = sc4 * 4;
        float4 v = (gr < n) ? *(const float4*)(s1 + (size_t)gr * 128 + c)
                            : make_float4(0.f, 0.f, 0.f, 0.f);
        float4 av = *(const float4*)&stats[c];
        float4 bv = *(const float4*)&stats[128 + c];
        v.x = fmaxf(fmaf(av.x, v.x, bv.x), 0.f);
        v.y = fmaxf(fmaf(av.y, v.y, bv.y), 0.f);
        v.z = fmaxf(fmaf(av.z, v.z, bv.z), 0.f);
        v.w = fmaxf(fmaf(av.w, v.w, bv.w), 0.f);
        xv[it] = v;
        wv[it] = *(const float4*)(wT2p + (size_t)(wrow + it * 8) * 128 + wjc * 4);
    }

    float acc[8][8] = {};

    for (int kt = 0; kt < 4; ++kt) {
        __syncthreads();
        #pragma unroll
        for (int it = 0; it < 4; ++it) {
            int row = srow + it * 32;
            xs[(sc4 * 4 + 0) * 132 + row] = xv[it].x;
            xs[(sc4 * 4 + 1) * 132 + row] = xv[it].y;
            xs[(sc4 * 4 + 2) * 132 + row] = xv[it].z;
            xs[(sc4 * 4 + 3) * 132 + row] = xv[it].w;
            *(float4*)&ws[(wrow + it * 8) * 132 + wjc * 4] = wv[it];
        }
        __syncthreads();
        if (kt < 3) {
            int k1 = kt + 1;
            int kbase = k1 * 32;
            #pragma unroll
            for (int it = 0; it < 4; ++it) {
                int gr = r0 + srow + it * 32;
                int c = kbase + sc4 * 4;
                float4 v = (gr < n) ? *(const float4*)(s1 + (size_t)gr * 128 + c)
                                    : make_float4(0.f, 0.f, 0.f, 0.f);
                float4 av = *(const float4*)&stats[c];
                float4 bv = *(const float4*)&stats[128 + c];
                v.x = fmaxf(fmaf(av.x, v.x, bv.x), 0.f);
                v.y = fmaxf(fmaf(av.y, v.y, bv.y), 0.f);
                v.z = fmaxf(fmaf(av.z, v.z, bv.z), 0.f);
                v.w = fmaxf(fmaf(av.w, v.w, bv.w), 0.f);
                xv[it] = v;
                wv[it] = *(const float4*)(wT2p + (size_t)(kbase + wrow + it * 8) * 128 + wjc * 4);
            }
        }
        #pragma unroll 4
        for (int k = 0; k < 32; ++k) {
            float4 x0 = *(const float4*)&xs[k * 132 + ty * 4];
            float4 x1 = *(const float4*)&xs[k * 132 + 64 + ty * 4];
            float4 w0 = *(const float4*)&ws[k * 132 + tx * 4];
            float4 w1 = *(const float4*)&ws[k * 132 + 64 + tx * 4];
            float xr[8] = {x0.x, x0.y, x0.z, x0.w, x1.x, x1.y, x1.z, x1.w};
            float wj[8] = {w0.x, w0.y, w0.z, w0.w, w1.x, w1.y, w1.z, w1.w};
            #pragma unroll
            for (int a = 0; a < 8; ++a)
                #pragma unroll
                for (int b = 0; b < 8; ++b)
                    acc[a][b] = fmaf(xr[a], wj[b], acc[a][b]);
        }
    }

    #pragma unroll
    for (int a = 0; a < 8; ++a) {
        int row = (a < 4) ? ty * 4 + a : 64 + ty * 4 + (a - 4);
        int gr = r0 + row;
        if (gr >= n) continue;
        #pragma unroll
        for (int b = 0; b < 8; ++b) {
            int j = (b < 4) ? tx * 4 + b : 64 + tx * 4 + (b - 4);
            if (j < 47)      y2p[(size_t)gr * 48 + j] = acc[a][b];
            else if (j < 94) rbuf[(size_t)gr * 47 + (j - 47)] = acc[a][b] + b2l[j - 47];
        }
    }
}

// ---- layer-2 gather + combine + L2-norm. One wave per node.
__global__ __launch_bounds__(256) void k_gather2_final(
        const float* __restrict__ y2p, const float* __restrict__ rbuf,
        const int* __restrict__ rowStart, const int* __restrict__ deg,
        const int* __restrict__ srcIdx, float* __restrict__ out, int n) {
    int t = threadIdx.x;
    int lane = t & 63, w = t >> 6;
    int node = blockIdx.x * 4 + w;
    if (node >= n) return;
    float v = 0.f;
    if (lane < 47) {
        int beg = rowStart[node], d = deg[node];
        float acc = 0.f;
        for (int e = beg; e < beg + d; ++e) {
            int s = srcIdx[e];
            acc += y2p[(size_t)s * 48 + lane];
        }
        v = acc / fmaxf((float)d, 1.0f) + rbuf[(size_t)node * 47 + lane];
    }
    float ss = warp_sum64(v * v);
    float inv = 1.0f / fmaxf(sqrtf(ss), 1e-12f);
    if (lane < 47) out[(size_t)node * 47 + lane] = v * inv;
}

extern "C" void kernel_launch(void* const* d_in, const int* in_sizes, int n_in,
                              void* d_out, int out_size, void* d_ws, size_t ws_size,
                              hipStream_t stream) {
    const float* x     = (const float*)d_in[0];
    const int*   ei    = (const int*)d_in[1];
    const float* w1l   = (const float*)d_in[2];
    const float* b1l   = (const float*)d_in[3];
    const float* w1r   = (const float*)d_in[4];
    const float* gamma = (const float*)d_in[5];
    const float* beta  = (const float*)d_in[6];
    const float* w2l   = (const float*)d_in[7];
    const float* b2l   = (const float*)d_in[8];
    const float* w2r   = (const float*)d_in[9];
    float* out = (float*)d_out;

    int n  = in_sizes[0] / 128;   // 100000
    int nE = in_sizes[1] / 2;     // 800000

    // ---- workspace layout ----
    // ints:   deg[n] | rowStart[n] | cursor[n] | srcIdx[nE] | blockSums[256]
    // floats: aggm[128n] (reused: y2p[48n] + rbuf[47n]) | s1[128n]
    //         | wT1[32768] | wT2p[16384] | stats[256]
    int* deg       = (int*)d_ws;
    int* rowStart  = deg + n;
    int* cursor    = rowStart + n;
    int* srcIdx    = cursor + n;
    int* blockSums = srcIdx + nE;
    float* aggm = (float*)(blockSums + 256);
    float* s1   = aggm + (size_t)n * 128;
    float* wT1  = s1 + (size_t)n * 128;
    float* wT2p = wT1 + 32768;
    float* stats = wT2p + 16384;
    float* y2p  = aggm;                       // stride 48 (aggm dead by then)
    float* rbuf = aggm + (size_t)n * 48;

    int nChunks = (n + 1023) / 1024;          // 98

    hipMemsetAsync(deg, 0, (size_t)n * sizeof(int), stream);
    hipMemsetAsync(stats, 0, 256 * sizeof(float), stream);

    k_wt<<<(256 * 128 + 128 * 128 + 255) / 256, 256, 0, stream>>>(w1l, w1r, w2l, w2r, wT1, wT2p);
    // CSR build
    k_hist<<<(nE + 255) / 256, 256, 0, stream>>>(ei, deg, nE);
    k_scan_blocks<<<nChunks, 256, 0, stream>>>(deg, rowStart, blockSums, n);
    k_scan_sums<<<1, 256, 0, stream>>>(blockSums, nChunks);
    k_scan_add<<<nChunks, 256, 0, stream>>>(rowStart, blockSums, cursor, n);
    k_fill<<<(nE + 255) / 256, 256, 0, stream>>>(ei, cursor, srcIdx, nE);
    // layer 1
    k_gather1<<<(n + 7) / 8, 256, 0, stream>>>(x, rowStart, deg, srcIdx, aggm, n);
    k_gemm1<<<(n + 127) / 128, 256, 0, stream>>>(x, aggm, wT1, b1l, s1, stats, n);
    k_bn_final<<<1, 128, 0, stream>>>(stats, gamma, beta, n);
    // layer 2
    k_gemm2<<<(n + 127) / 128, 256, 0, stream>>>(s1, wT2p, stats, b2l, y2p, rbuf, n);
    k_gather2_final<<<(n + 3) / 4, 256, 0, stream>>>(y2p, rbuf, rowStart, deg, srcIdx, out, n);
}

// Round 5
// 504.902 us; speedup vs baseline: 5.4905x; 1.0781x over previous
//
#include <hip/hip_runtime.h>
#include <cstdint>

// GNN: 2-layer GraphSAGE (mean aggr, L2-normalize) + BatchNorm(train) + ReLU.
// N=100000 nodes, E=800000 edges, C: 128 -> 128 -> 47.
//
// Round 5:
//  - GEMM blocks 128x128 -> 64x128: grid 782 -> 1563 (6.1 blocks/CU), LDS
//    25.6 KB -> 6 blocks/CU resident. R4's 22% occupancy was grid-capped.
//  - Register prefetch REMOVED: R4's +70 MB WRITE_SIZE at VGPR=64 was scratch
//    spill traffic from the prefetch registers; net regression. Clean
//    2-barrier staging + high occupancy (m114 implicit overlap) instead.
//  - gather1 / gather2_final: 2-edge unrolled, dual accumulators (ILP).
//  - BN stays fused in gemm1 epilogue (stats) / gemm2 staging (apply+relu).

static __device__ __forceinline__ float warp_sum64(float v) {
    #pragma unroll
    for (int off = 32; off > 0; off >>= 1) v += __shfl_xor(v, off, 64);
    return v;
}

// ---- weight transposes: wT1[k][128] (k<128: w1l, else w1r),
// ---- wT2p[k][128] (j<47: w2l, j<94: w2r, else 0)
__global__ __launch_bounds__(256) void k_wt(
        const float* __restrict__ w1l, const float* __restrict__ w1r,
        const float* __restrict__ w2l, const float* __restrict__ w2r,
        float* __restrict__ wT1, float* __restrict__ wT2p) {
    int idx = blockIdx.x * 256 + threadIdx.x;
    if (idx < 256 * 128) {
        int k = idx >> 7, j = idx & 127;
        wT1[idx] = (k < 128) ? w1l[j * 128 + k] : w1r[j * 128 + (k - 128)];
    } else if (idx < 256 * 128 + 128 * 128) {
        int i2 = idx - 256 * 128;
        int k = i2 >> 7, j = i2 & 127;
        float v = 0.f;
        if (j < 47)      v = w2l[j * 128 + k];
        else if (j < 94) v = w2r[(j - 47) * 128 + k];
        wT2p[i2] = v;
    }
}

// ---- CSR build ----------------------------------------------------------
__global__ __launch_bounds__(256) void k_hist(
        const int* __restrict__ ei, int* __restrict__ deg, int nE) {
    int g = blockIdx.x * 256 + threadIdx.x;
    if (g < nE) atomicAdd(&deg[ei[nE + g]], 1);
}

__global__ __launch_bounds__(256) void k_scan_blocks(
        const int* __restrict__ deg, int* __restrict__ rowStart,
        int* __restrict__ blockSums, int n) {
    int t = threadIdx.x;
    int base = blockIdx.x * 1024 + t * 4;
    int v[4]; int s = 0;
    #pragma unroll
    for (int u = 0; u < 4; ++u) { v[u] = (base + u < n) ? deg[base + u] : 0; s += v[u]; }
    __shared__ int sh[256];
    sh[t] = s;
    __syncthreads();
    for (int off = 1; off < 256; off <<= 1) {
        int add = (t >= off) ? sh[t - off] : 0;
        __syncthreads();
        sh[t] += add;
        __syncthreads();
    }
    int excl = sh[t] - s;
    #pragma unroll
    for (int u = 0; u < 4; ++u) { if (base + u < n) rowStart[base + u] = excl; excl += v[u]; }
    if (t == 255) blockSums[blockIdx.x] = sh[255];
}

__global__ void k_scan_sums(int* blockSums, int nb) {
    __shared__ int sh[256];
    int t = threadIdx.x;
    int s = (t < nb) ? blockSums[t] : 0;
    sh[t] = s;
    __syncthreads();
    for (int off = 1; off < 256; off <<= 1) {
        int add = (t >= off) ? sh[t - off] : 0;
        __syncthreads();
        sh[t] += add;
        __syncthreads();
    }
    if (t < nb) blockSums[t] = sh[t] - s;  // exclusive
}

__global__ __launch_bounds__(256) void k_scan_add(
        int* __restrict__ rowStart, const int* __restrict__ blockSums,
        int* __restrict__ cursor, int n) {
    int off = blockSums[blockIdx.x];
    #pragma unroll
    for (int u = 0; u < 4; ++u) {
        int i = blockIdx.x * 1024 + threadIdx.x + u * 256;
        if (i < n) { int r = rowStart[i] + off; rowStart[i] = r; cursor[i] = r; }
    }
}

__global__ __launch_bounds__(256) void k_fill(
        const int* __restrict__ ei, int* __restrict__ cursor,
        int* __restrict__ srcIdx, int nE) {
    int g = blockIdx.x * 256 + threadIdx.x;
    if (g >= nE) return;
    int s = ei[g];
    int d = ei[nE + g];
    int p = atomicAdd(&cursor[d], 1);
    srcIdx[p] = s;
}

// ---- layer-1 gather: 32 lanes/node, lane owns one float4; 2-edge unroll.
__global__ __launch_bounds__(256) void k_gather1(
        const float* __restrict__ x, const int* __restrict__ rowStart,
        const int* __restrict__ deg, const int* __restrict__ srcIdx,
        float* __restrict__ aggm, int n) {
    int t = threadIdx.x;
    int q = t & 31, grp = t >> 5;
    int node = blockIdx.x * 8 + grp;
    if (node >= n) return;
    int beg = rowStart[node];
    int d = deg[node];
    int end = beg + d;
    float4 a0 = make_float4(0.f, 0.f, 0.f, 0.f);
    float4 a1 = make_float4(0.f, 0.f, 0.f, 0.f);
    int e = beg;
    for (; e + 2 <= end; e += 2) {
        int s0 = srcIdx[e];
        int s1v = srcIdx[e + 1];
        float4 v0 = *(const float4*)(x + (size_t)s0 * 128 + q * 4);
        float4 v1 = *(const float4*)(x + (size_t)s1v * 128 + q * 4);
        a0.x += v0.x; a0.y += v0.y; a0.z += v0.z; a0.w += v0.w;
        a1.x += v1.x; a1.y += v1.y; a1.z += v1.z; a1.w += v1.w;
    }
    if (e < end) {
        int s0 = srcIdx[e];
        float4 v0 = *(const float4*)(x + (size_t)s0 * 128 + q * 4);
        a0.x += v0.x; a0.y += v0.y; a0.z += v0.z; a0.w += v0.w;
    }
    float ic = 1.0f / fmaxf((float)d, 1.0f);
    float4 r = make_float4((a0.x + a1.x) * ic, (a0.y + a1.y) * ic,
                           (a0.z + a1.z) * ic, (a0.w + a1.w) * ic);
    *(float4*)(aggm + (size_t)node * 128 + q * 4) = r;
}

// ---- GEMM1: 64 rows x 128 cols/block, thread = 4x8 (split cols), K=256.
// s1 = L2norm_rows( aggm @ w1l^T + b1l + x @ w1r^T ); accumulates per-channel
// sum/sumsq of s1 into stats (atomics per block).
__global__ __launch_bounds__(256, 6) void k_gemm1(
        const float* __restrict__ x, const float* __restrict__ aggm,
        const float* __restrict__ wT, const float* __restrict__ b1l,
        float* __restrict__ s1, float* __restrict__ stats, int n) {
    __shared__ float xs[32 * 68];    // [k][row], stride 68 (2176 floats)
    __shared__ float ws[32 * 132];   // [k][j],   stride 132 (4224 floats)
    int t = threadIdx.x;
    int tx = t & 15, ty = t >> 4;    // tx: col octet (split 4+4), ty: 4 rows
    int r0 = blockIdx.x * 64;

    float acc[4][8] = {};

    for (int kt = 0; kt < 8; ++kt) {
        const float* src = (kt < 4) ? aggm : x;
        int kbase = (kt & 3) * 32;
        __syncthreads();
        // x-tile: 64 rows x 32 k -> transposed; 512 float4, 2 per thread
        #pragma unroll
        for (int it = 0; it < 2; ++it) {
            int i = t + it * 256;       // 0..511
            int row = i >> 3, c4 = i & 7;
            int gr = r0 + row;
            float4 v = (gr < n) ? *(const float4*)(src + (size_t)gr * 128 + kbase + c4 * 4)
                                : make_float4(0.f, 0.f, 0.f, 0.f);
            xs[(c4 * 4 + 0) * 68 + row] = v.x;
            xs[(c4 * 4 + 1) * 68 + row] = v.y;
            xs[(c4 * 4 + 2) * 68 + row] = v.z;
            xs[(c4 * 4 + 3) * 68 + row] = v.w;
        }
        // w-tile: 32 k x 128 j; 1024 float4, 4 per thread
        #pragma unroll
        for (int it = 0; it < 4; ++it) {
            int i = t + it * 256;
            int krow = i >> 5, jc = i & 31;
            *(float4*)&ws[krow * 132 + jc * 4] =
                *(const float4*)(wT + (size_t)(kt * 32 + krow) * 128 + jc * 4);
        }
        __syncthreads();
        #pragma unroll 4
        for (int k = 0; k < 32; ++k) {
            float4 xr4 = *(const float4*)&xs[k * 68 + ty * 4];
            float4 w0  = *(const float4*)&ws[k * 132 + tx * 4];
            float4 w1  = *(const float4*)&ws[k * 132 + 64 + tx * 4];
            float xr[4] = {xr4.x, xr4.y, xr4.z, xr4.w};
            float wj[8] = {w0.x, w0.y, w0.z, w0.w, w1.x, w1.y, w1.z, w1.w};
            #pragma unroll
            for (int a = 0; a < 4; ++a)
                #pragma unroll
                for (int b = 0; b < 8; ++b)
                    acc[a][b] = fmaf(xr[a], wj[b], acc[a][b]);
        }
    }

    // bias
    #pragma unroll
    for (int b = 0; b < 8; ++b) {
        int j = (b < 4) ? tx * 4 + b : 64 + tx * 4 + (b - 4);
        float bj = b1l[j];
        #pragma unroll
        for (int a = 0; a < 4; ++a) acc[a][b] += bj;
    }

    // row L2-norm partials: red[row*17 + tx]
    __syncthreads();
    #pragma unroll
    for (int a = 0; a < 4; ++a) {
        float p = 0.f;
        #pragma unroll
        for (int b = 0; b < 8; ++b) p += acc[a][b] * acc[a][b];
        xs[(ty * 4 + a) * 17 + tx] = p;
    }
    __syncthreads();
    if (t < 64) {
        float s = 0.f;
        #pragma unroll
        for (int i = 0; i < 16; ++i) s += xs[t * 17 + i];
        ws[t] = 1.0f / fmaxf(sqrtf(s), 1e-12f);
    }
    __syncthreads();
    // scale + store + per-channel stats partials
    float colS[8] = {}, colQ[8] = {};
    #pragma unroll
    for (int a = 0; a < 4; ++a) {
        int row = ty * 4 + a;
        int gr = r0 + row;
        if (gr >= n) continue;
        float iv = ws[row];
        float v[8];
        #pragma unroll
        for (int b = 0; b < 8; ++b) {
            v[b] = acc[a][b] * iv;
            colS[b] += v[b];
            colQ[b] += v[b] * v[b];
        }
        *(float4*)(s1 + (size_t)gr * 128 + tx * 4)      = make_float4(v[0], v[1], v[2], v[3]);
        *(float4*)(s1 + (size_t)gr * 128 + 64 + tx * 4) = make_float4(v[4], v[5], v[6], v[7]);
    }
    __syncthreads();
    #pragma unroll
    for (int b = 0; b < 8; ++b) {
        int j = (b < 4) ? tx * 4 + b : 64 + tx * 4 + (b - 4);
        xs[j * 17 + ty] = colS[b];     // 128*17 = 2176 floats, fits exactly
        ws[j * 17 + ty] = colQ[b];
    }
    __syncthreads();
    if (t < 128) {
        float s = 0.f, q = 0.f;
        #pragma unroll
        for (int i = 0; i < 16; ++i) { s += xs[t * 17 + i]; q += ws[t * 17 + i]; }
        atomicAdd(&stats[t], s);
        atomicAdd(&stats[128 + t], q);
    }
}

// ---- BN coefficient finalize: stats -> (a, b) per channel
__global__ void k_bn_final(float* stats, const float* __restrict__ gamma,
                           const float* __restrict__ beta, int n) {
    int c = threadIdx.x;  // 128
    float s = stats[c], q = stats[128 + c];
    float fn = (float)n;
    float mean = s / fn;
    float var = q / fn - mean * mean;   // biased variance
    float istd = rsqrtf(var + 1e-5f);
    float a = gamma[c] * istd;
    float b = beta[c] - mean * a;
    stats[c] = a;
    stats[128 + c] = b;
}

// ---- GEMM2: relu(BN(s1)) @ wT2p -> y2p[N,48] (j<47) + rbuf[N,47] (+b2l).
__global__ __launch_bounds__(256, 6) void k_gemm2(
        const float* __restrict__ s1, const float* __restrict__ wT2p,
        const float* __restrict__ stats, const float* __restrict__ b2l,
        float* __restrict__ y2p, float* __restrict__ rbuf, int n) {
    __shared__ float xs[32 * 68];
    __shared__ float ws[32 * 132];
    int t = threadIdx.x;
    int tx = t & 15, ty = t >> 4;
    int r0 = blockIdx.x * 64;

    float acc[4][8] = {};

    for (int kt = 0; kt < 4; ++kt) {
        int kbase = kt * 32;
        __syncthreads();
        #pragma unroll
        for (int it = 0; it < 2; ++it) {
            int i = t + it * 256;
            int row = i >> 3, c4 = i & 7;
            int gr = r0 + row;
            int c = kbase + c4 * 4;
            float4 v = (gr < n) ? *(const float4*)(s1 + (size_t)gr * 128 + c)
                                : make_float4(0.f, 0.f, 0.f, 0.f);
            float4 av = *(const float4*)&stats[c];
            float4 bv = *(const float4*)&stats[128 + c];
            v.x = fmaxf(fmaf(av.x, v.x, bv.x), 0.f);
            v.y = fmaxf(fmaf(av.y, v.y, bv.y), 0.f);
            v.z = fmaxf(fmaf(av.z, v.z, bv.z), 0.f);
            v.w = fmaxf(fmaf(av.w, v.w, bv.w), 0.f);
            xs[(c4 * 4 + 0) * 68 + row] = v.x;
            xs[(c4 * 4 + 1) * 68 + row] = v.y;
            xs[(c4 * 4 + 2) * 68 + row] = v.z;
            xs[(c4 * 4 + 3) * 68 + row] = v.w;
        }
        #pragma unroll
        for (int it = 0; it < 4; ++it) {
            int i = t + it * 256;
            int krow = i >> 5, jc = i & 31;
            *(float4*)&ws[krow * 132 + jc * 4] =
                *(const float4*)(wT2p + (size_t)(kbase + krow) * 128 + jc * 4);
        }
        __syncthreads();
        #pragma unroll 4
        for (int k = 0; k < 32; ++k) {
            float4 xr4 = *(const float4*)&xs[k * 68 + ty * 4];
            float4 w0  = *(const float4*)&ws[k * 132 + tx * 4];
            float4 w1  = *(const float4*)&ws[k * 132 + 64 + tx * 4];
            float xr[4] = {xr4.x, xr4.y, xr4.z, xr4.w};
            float wj[8] = {w0.x, w0.y, w0.z, w0.w, w1.x, w1.y, w1.z, w1.w};
            #pragma unroll
            for (int a = 0; a < 4; ++a)
                #pragma unroll
                for (int b = 0; b < 8; ++b)
                    acc[a][b] = fmaf(xr[a], wj[b], acc[a][b]);
        }
    }

    #pragma unroll
    for (int a = 0; a < 4; ++a) {
        int gr = r0 + ty * 4 + a;
        if (gr >= n) continue;
        #pragma unroll
        for (int b = 0; b < 8; ++b) {
            int j = (b < 4) ? tx * 4 + b : 64 + tx * 4 + (b - 4);
            if (j < 47)      y2p[(size_t)gr * 48 + j] = acc[a][b];
            else if (j < 94) rbuf[(size_t)gr * 47 + (j - 47)] = acc[a][b] + b2l[j - 47];
        }
    }
}

// ---- layer-2 gather + combine + L2-norm. One wave/node, 2-edge unroll.
__global__ __launch_bounds__(256) void k_gather2_final(
        const float* __restrict__ y2p, const float* __restrict__ rbuf,
        const int* __restrict__ rowStart, const int* __restrict__ deg,
        const int* __restrict__ srcIdx, float* __restrict__ out, int n) {
    int t = threadIdx.x;
    int lane = t & 63, w = t >> 6;
    int node = blockIdx.x * 4 + w;
    if (node >= n) return;
    int beg = rowStart[node];
    int d = deg[node];
    float v = 0.f;
    if (lane < 47) {
        int end = beg + d;
        float acc0 = 0.f, acc1 = 0.f;
        int e = beg;
        for (; e + 2 <= end; e += 2) {
            int s0 = srcIdx[e];
            int s1v = srcIdx[e + 1];
            acc0 += y2p[(size_t)s0 * 48 + lane];
            acc1 += y2p[(size_t)s1v * 48 + lane];
        }
        if (e < end) acc0 += y2p[(size_t)srcIdx[e] * 48 + lane];
        v = (acc0 + acc1) / fmaxf((float)d, 1.0f) + rbuf[(size_t)node * 47 + lane];
    }
    float ss = warp_sum64(v * v);
    float inv = 1.0f / fmaxf(sqrtf(ss), 1e-12f);
    if (lane < 47) out[(size_t)node * 47 + lane] = v * inv;
}

extern "C" void kernel_launch(void* const* d_in, const int* in_sizes, int n_in,
                              void* d_out, int out_size, void* d_ws, size_t ws_size,
                              hipStream_t stream) {
    const float* x     = (const float*)d_in[0];
    const int*   ei    = (const int*)d_in[1];
    const float* w1l   = (const float*)d_in[2];
    const float* b1l   = (const float*)d_in[3];
    const float* w1r   = (const float*)d_in[4];
    const float* gamma = (const float*)d_in[5];
    const float* beta  = (const float*)d_in[6];
    const float* w2l   = (const float*)d_in[7];
    const float* b2l   = (const float*)d_in[8];
    const float* w2r   = (const float*)d_in[9];
    float* out = (float*)d_out;

    int n  = in_sizes[0] / 128;   // 100000
    int nE = in_sizes[1] / 2;     // 800000

    // ---- workspace layout ----
    // deg[n](int) | stats[256](f32) | rowStart[n] | cursor[n] | srcIdx[nE]
    // | blockSums[256] | aggm[128n] (reused: y2p[48n]+rbuf[47n]) | s1[128n]
    // | wT1[32768] | wT2p[16384]
    int* deg       = (int*)d_ws;
    float* stats   = (float*)(deg + n);
    int* rowStart  = (int*)(stats + 256);
    int* cursor    = rowStart + n;
    int* srcIdx    = cursor + n;
    int* blockSums = srcIdx + nE;
    float* aggm = (float*)(blockSums + 256);
    float* s1   = aggm + (size_t)n * 128;
    float* wT1  = s1 + (size_t)n * 128;
    float* wT2p = wT1 + 32768;
    float* y2p  = aggm;                       // stride 48 (aggm dead by then)
    float* rbuf = aggm + (size_t)n * 48;

    int nChunks = (n + 1023) / 1024;          // 98

    hipMemsetAsync(deg, 0, ((size_t)n + 256) * sizeof(int), stream);  // deg + stats

    k_wt<<<(256 * 128 + 128 * 128 + 255) / 256, 256, 0, stream>>>(w1l, w1r, w2l, w2r, wT1, wT2p);
    // CSR build
    k_hist<<<(nE + 255) / 256, 256, 0, stream>>>(ei, deg, nE);
    k_scan_blocks<<<nChunks, 256, 0, stream>>>(deg, rowStart, blockSums, n);
    k_scan_sums<<<1, 256, 0, stream>>>(blockSums, nChunks);
    k_scan_add<<<nChunks, 256, 0, stream>>>(rowStart, blockSums, cursor, n);
    k_fill<<<(nE + 255) / 256, 256, 0, stream>>>(ei, cursor, srcIdx, nE);
    // layer 1
    k_gather1<<<(n + 7) / 8, 256, 0, stream>>>(x, rowStart, deg, srcIdx, aggm, n);
    k_gemm1<<<(n + 63) / 64, 256, 0, stream>>>(x, aggm, wT1, b1l, s1, stats, n);
    k_bn_final<<<1, 128, 0, stream>>>(stats, gamma, beta, n);
    // layer 2
    k_gemm2<<<(n + 63) / 64, 256, 0, stream>>>(s1, wT2p, stats, b2l, y2p, rbuf, n);
    k_gather2_final<<<(n + 3) / 4, 256, 0, stream>>>(y2p, rbuf, rowStart, deg, srcIdx, out, n);
}

// Round 6
// 370.253 us; speedup vs baseline: 7.4871x; 1.3637x over previous
//
#include <hip/hip_runtime.h>
#include <cstdint>

// GNN: 2-layer GraphSAGE (mean aggr, L2-normalize) + BatchNorm(train) + ReLU.
// N=100000 nodes, E=800000 edges, C: 128 -> 128 -> 47.
//
// Round 6: fp32 vector GEMM measured at 111 TF = the fp32 VALU roofline
// (m07: 103 TF). Switch GEMMs to bf16 MFMA (16x16x32, fp32 accum):
//  - x, aggm, s1(h), weights carried as bf16; single RNE rounding points.
//  - 128x128 block, 4 waves, each wave 64x64 = 16 MFMA per K32-tile,
//    8 ds_read_b128 per 16 MFMA (m97 ratio). LDS row stride 40 bf16 ->
//    max 2-way bank aliasing (free, m136).
//  - gather1 reads bf16 x copy (half the gather traffic, LLC-resident).
//  - BN stats fused in gemm1 epilogue; BN+relu applied in gemm2 staging.

typedef __attribute__((ext_vector_type(8))) short s8v;
typedef __attribute__((ext_vector_type(4))) float fx4;

static __device__ __forceinline__ float bf2f(unsigned short h) {
    union { unsigned int u; float f; } c; c.u = (unsigned int)h << 16; return c.f;
}
static __device__ __forceinline__ unsigned short f2bf(float f) {
    union { float f; unsigned int u; } c; c.f = f;
    unsigned int u = c.u;
    return (unsigned short)((u + 0x7FFF + ((u >> 16) & 1)) >> 16);   // RNE
}

static __device__ __forceinline__ float warp_sum64(float v) {
    #pragma unroll
    for (int off = 32; off > 0; off >>= 1) v += __shfl_xor(v, off, 64);
    return v;
}

// ---- weights -> bf16, [j][k] row-major (k contiguous = MFMA B layout).
// wB1[j=0..127][k=0..255] (k<128: w1l, else w1r); wB2p[j=0..127][k=0..127]
// (j<47: w2l, j<94: w2r, else 0).
__global__ __launch_bounds__(256) void k_wt(
        const float* __restrict__ w1l, const float* __restrict__ w1r,
        const float* __restrict__ w2l, const float* __restrict__ w2r,
        unsigned short* __restrict__ wB1, unsigned short* __restrict__ wB2p) {
    int idx = blockIdx.x * 256 + threadIdx.x;
    if (idx < 128 * 256) {
        int j = idx >> 8, k = idx & 255;
        float v = (k < 128) ? w1l[j * 128 + k] : w1r[j * 128 + (k - 128)];
        wB1[idx] = f2bf(v);
    } else if (idx < 128 * 256 + 128 * 128) {
        int i2 = idx - 128 * 256;
        int j = i2 >> 7, k = i2 & 127;
        float v = 0.f;
        if (j < 47)      v = w2l[j * 128 + k];
        else if (j < 94) v = w2r[(j - 47) * 128 + k];
        wB2p[i2] = f2bf(v);
    }
}

// ---- x (fp32) -> xb (bf16), 8 elements/thread
__global__ __launch_bounds__(256) void k_xcast(
        const float* __restrict__ x, unsigned short* __restrict__ xb, int n) {
    int i = blockIdx.x * 256 + threadIdx.x;      // group of 8 floats
    if (i >= n * 16) return;
    float4 a = ((const float4*)x)[i * 2];
    float4 b = ((const float4*)x)[i * 2 + 1];
    union { s8v v; unsigned short u[8]; } o;
    o.u[0] = f2bf(a.x); o.u[1] = f2bf(a.y); o.u[2] = f2bf(a.z); o.u[3] = f2bf(a.w);
    o.u[4] = f2bf(b.x); o.u[5] = f2bf(b.y); o.u[6] = f2bf(b.z); o.u[7] = f2bf(b.w);
    ((s8v*)xb)[i] = o.v;
}

// ---- CSR build ----------------------------------------------------------
__global__ __launch_bounds__(256) void k_hist(
        const int* __restrict__ ei, int* __restrict__ deg, int nE) {
    int g = blockIdx.x * 256 + threadIdx.x;
    if (g < nE) atomicAdd(&deg[ei[nE + g]], 1);
}

__global__ __launch_bounds__(256) void k_scan_blocks(
        const int* __restrict__ deg, int* __restrict__ rowStart,
        int* __restrict__ blockSums, int n) {
    int t = threadIdx.x;
    int base = blockIdx.x * 1024 + t * 4;
    int v[4]; int s = 0;
    #pragma unroll
    for (int u = 0; u < 4; ++u) { v[u] = (base + u < n) ? deg[base + u] : 0; s += v[u]; }
    __shared__ int sh[256];
    sh[t] = s;
    __syncthreads();
    for (int off = 1; off < 256; off <<= 1) {
        int add = (t >= off) ? sh[t - off] : 0;
        __syncthreads();
        sh[t] += add;
        __syncthreads();
    }
    int excl = sh[t] - s;
    #pragma unroll
    for (int u = 0; u < 4; ++u) { if (base + u < n) rowStart[base + u] = excl; excl += v[u]; }
    if (t == 255) blockSums[blockIdx.x] = sh[255];
}

__global__ void k_scan_sums(int* blockSums, int nb) {
    __shared__ int sh[256];
    int t = threadIdx.x;
    int s = (t < nb) ? blockSums[t] : 0;
    sh[t] = s;
    __syncthreads();
    for (int off = 1; off < 256; off <<= 1) {
        int add = (t >= off) ? sh[t - off] : 0;
        __syncthreads();
        sh[t] += add;
        __syncthreads();
    }
    if (t < nb) blockSums[t] = sh[t] - s;  // exclusive
}

__global__ __launch_bounds__(256) void k_scan_add(
        int* __restrict__ rowStart, const int* __restrict__ blockSums,
        int* __restrict__ cursor, int n) {
    int off = blockSums[blockIdx.x];
    #pragma unroll
    for (int u = 0; u < 4; ++u) {
        int i = blockIdx.x * 1024 + threadIdx.x + u * 256;
        if (i < n) { int r = rowStart[i] + off; rowStart[i] = r; cursor[i] = r; }
    }
}

__global__ __launch_bounds__(256) void k_fill(
        const int* __restrict__ ei, int* __restrict__ cursor,
        int* __restrict__ srcIdx, int nE) {
    int g = blockIdx.x * 256 + threadIdx.x;
    if (g >= nE) return;
    int s = ei[g];
    int d = ei[nE + g];
    int p = atomicAdd(&cursor[d], 1);
    srcIdx[p] = s;
}

// ---- layer-1 gather (bf16 in/out): 16 lanes/node, lane owns 8 channels.
__global__ __launch_bounds__(256) void k_gather1(
        const unsigned short* __restrict__ xb, const int* __restrict__ rowStart,
        const int* __restrict__ deg, const int* __restrict__ srcIdx,
        unsigned short* __restrict__ aggb, int n) {
    int t = threadIdx.x;
    int q = t & 15, grp = t >> 4;
    int node = blockIdx.x * 16 + grp;
    if (node >= n) return;
    int beg = rowStart[node];
    int d = deg[node];
    int end = beg + d;
    float a0[8] = {}, a1[8] = {};
    int e = beg;
    for (; e + 2 <= end; e += 2) {
        int s0 = srcIdx[e];
        int s1v = srcIdx[e + 1];
        s8v v0 = *(const s8v*)(xb + (size_t)s0 * 128 + q * 8);
        s8v v1 = *(const s8v*)(xb + (size_t)s1v * 128 + q * 8);
        #pragma unroll
        for (int u = 0; u < 8; ++u) {
            a0[u] += bf2f((unsigned short)v0[u]);
            a1[u] += bf2f((unsigned short)v1[u]);
        }
    }
    if (e < end) {
        s8v v0 = *(const s8v*)(xb + (size_t)srcIdx[e] * 128 + q * 8);
        #pragma unroll
        for (int u = 0; u < 8; ++u) a0[u] += bf2f((unsigned short)v0[u]);
    }
    float ic = 1.0f / fmaxf((float)d, 1.0f);
    union { s8v v; unsigned short u[8]; } o;
    #pragma unroll
    for (int u = 0; u < 8; ++u) o.u[u] = f2bf((a0[u] + a1[u]) * ic);
    *(s8v*)(aggb + (size_t)node * 128 + q * 8) = o.v;
}

// ---- GEMM1 (bf16 MFMA): block 128x128, K=256 (aggb then xb).
// s1b = bf16( L2norm_rows( aggm @ w1l^T + b1l + x @ w1r^T ) );
// accumulates per-channel sum/sumsq of s1 into stats (1 atomic pair/ch/block).
__global__ __launch_bounds__(256, 3) void k_gemm1(
        const unsigned short* __restrict__ xb, const unsigned short* __restrict__ aggb,
        const unsigned short* __restrict__ wB1, const float* __restrict__ b1l,
        unsigned short* __restrict__ s1b, float* __restrict__ stats, int n) {
    __shared__ __align__(16) unsigned short xs[128 * 40];   // [row][k] stride 40
    __shared__ __align__(16) unsigned short ws[128 * 40];   // [j][k]   stride 40
    int t = threadIdx.x;
    int w = t >> 6, L = t & 63;
    int q = L >> 4, lm = L & 15;
    int wr0 = (w >> 1) * 64;     // wave row base within block
    int wc0 = (w & 1) * 64;      // wave col base
    int r0 = blockIdx.x * 128;

    fx4 acc[4][4];
    fx4 z4 = {0.f, 0.f, 0.f, 0.f};
    #pragma unroll
    for (int r = 0; r < 4; ++r)
        #pragma unroll
        for (int c = 0; c < 4; ++c) acc[r][c] = z4;

    for (int kt = 0; kt < 8; ++kt) {
        const unsigned short* src = (kt < 4) ? aggb : xb;
        int kbase = (kt & 3) * 32;
        __syncthreads();
        #pragma unroll
        for (int it = 0; it < 2; ++it) {
            int i = t + it * 256;            // 0..511
            int row = i >> 2, kq = i & 3;
            int gr = r0 + row;
            s8v v = {0, 0, 0, 0, 0, 0, 0, 0};
            if (gr < n) v = *(const s8v*)(src + (size_t)gr * 128 + kbase + kq * 8);
            *(s8v*)&xs[row * 40 + kq * 8] = v;
            s8v wv = *(const s8v*)(wB1 + (size_t)row * 256 + kt * 32 + kq * 8);
            *(s8v*)&ws[row * 40 + kq * 8] = wv;
        }
        __syncthreads();
        s8v af[4], bf[4];
        #pragma unroll
        for (int r = 0; r < 4; ++r)
            af[r] = *(const s8v*)&xs[(wr0 + r * 16 + lm) * 40 + q * 8];
        #pragma unroll
        for (int c = 0; c < 4; ++c)
            bf[c] = *(const s8v*)&ws[(wc0 + c * 16 + lm) * 40 + q * 8];
        #pragma unroll
        for (int r = 0; r < 4; ++r)
            #pragma unroll
            for (int c = 0; c < 4; ++c)
                acc[r][c] = __builtin_amdgcn_mfma_f32_16x16x32_bf16(af[r], bf[c], acc[r][c], 0, 0, 0);
    }

    // ---- epilogue: bias -> row L2-norm -> scale -> bf16 store -> BN stats
    float bj[4];
    #pragma unroll
    for (int c = 0; c < 4; ++c) bj[c] = b1l[wc0 + c * 16 + lm];
    #pragma unroll
    for (int r = 0; r < 4; ++r)
        #pragma unroll
        for (int c = 0; c < 4; ++c) acc[r][c] += bj[c];

    fx4 pr[4];
    #pragma unroll
    for (int r = 0; r < 4; ++r) {
        fx4 p = acc[r][0] * acc[r][0];
        #pragma unroll
        for (int c = 1; c < 4; ++c) p += acc[r][c] * acc[r][c];
        #pragma unroll
        for (int off = 1; off <= 8; off <<= 1)
            #pragma unroll
            for (int i2 = 0; i2 < 4; ++i2) p[i2] += __shfl_xor(p[i2], off, 64);
        pr[r] = p;
    }

    __syncthreads();   // all waves done with xs/ws -> safe to overlay
    float* norm2 = (float*)xs;          // [128][2]
    float* invn  = (float*)xs + 256;    // [128]
    float* statS = (float*)ws;          // [128][2]
    float* statQ = (float*)ws + 256;    // [128][2]
    if (lm == 0) {
        #pragma unroll
        for (int r = 0; r < 4; ++r)
            #pragma unroll
            for (int i = 0; i < 4; ++i)
                norm2[(wr0 + r * 16 + q * 4 + i) * 2 + (w & 1)] = pr[r][i];
    }
    __syncthreads();
    if (t < 128) {
        float s = norm2[t * 2] + norm2[t * 2 + 1];
        invn[t] = 1.0f / fmaxf(sqrtf(s), 1e-12f);
    }
    __syncthreads();

    float cS[4] = {}, cQ[4] = {};
    #pragma unroll
    for (int r = 0; r < 4; ++r) {
        int rowb = wr0 + r * 16 + q * 4;
        fx4 iv = *(const fx4*)&invn[rowb];
        #pragma unroll
        for (int c = 0; c < 4; ++c) {
            fx4 v = acc[r][c] * iv;
            int col = wc0 + c * 16 + lm;
            #pragma unroll
            for (int i = 0; i < 4; ++i) {
                int gr = r0 + rowb + i;
                if (gr < n) {
                    s1b[(size_t)gr * 128 + col] = f2bf(v[i]);
                    cS[c] += v[i];
                    cQ[c] += v[i] * v[i];
                }
            }
        }
    }
    #pragma unroll
    for (int off = 16; off <= 32; off <<= 1)
        #pragma unroll
        for (int c = 0; c < 4; ++c) {
            cS[c] += __shfl_xor(cS[c], off, 64);
            cQ[c] += __shfl_xor(cQ[c], off, 64);
        }
    if (q == 0) {
        #pragma unroll
        for (int c = 0; c < 4; ++c) {
            int col = wc0 + c * 16 + lm;
            statS[col * 2 + (w >> 1)] = cS[c];
            statQ[col * 2 + (w >> 1)] = cQ[c];
        }
    }
    __syncthreads();
    if (t < 128) {
        atomicAdd(&stats[t],       statS[t * 2] + statS[t * 2 + 1]);
        atomicAdd(&stats[128 + t], statQ[t * 2] + statQ[t * 2 + 1]);
    }
}

// ---- BN coefficient finalize: stats -> (a, b) per channel
__global__ void k_bn_final(float* stats, const float* __restrict__ gamma,
                           const float* __restrict__ beta, int n) {
    int c = threadIdx.x;  // 128
    float s = stats[c], q = stats[128 + c];
    float fn = (float)n;
    float mean = s / fn;
    float var = q / fn - mean * mean;   // biased variance
    float istd = rsqrtf(var + 1e-5f);
    float a = gamma[c] * istd;
    float b = beta[c] - mean * a;
    stats[c] = a;
    stats[128 + c] = b;
}

// ---- GEMM2 (bf16 MFMA): h = relu(BN(s1b)) applied at staging.
// h @ [w2l|w2r]^T -> y2p[N,48] (j<47) + rbuf[N,47] (j 47..93, +b2l).
__global__ __launch_bounds__(256, 3) void k_gemm2(
        const unsigned short* __restrict__ s1b, const unsigned short* __restrict__ wB2p,
        const float* __restrict__ stats, const float* __restrict__ b2l,
        float* __restrict__ y2p, float* __restrict__ rbuf, int n) {
    __shared__ __align__(16) unsigned short xs[128 * 40];
    __shared__ __align__(16) unsigned short ws[128 * 40];
    int t = threadIdx.x;
    int w = t >> 6, L = t & 63;
    int q = L >> 4, lm = L & 15;
    int wr0 = (w >> 1) * 64, wc0 = (w & 1) * 64;
    int r0 = blockIdx.x * 128;

    fx4 acc[4][4];
    fx4 z4 = {0.f, 0.f, 0.f, 0.f};
    #pragma unroll
    for (int r = 0; r < 4; ++r)
        #pragma unroll
        for (int c = 0; c < 4; ++c) acc[r][c] = z4;

    for (int kt = 0; kt < 4; ++kt) {
        int kbase = kt * 32;
        __syncthreads();
        #pragma unroll
        for (int it = 0; it < 2; ++it) {
            int i = t + it * 256;
            int row = i >> 2, kq = i & 3;
            int gr = r0 + row;
            int cb = kbase + kq * 8;
            s8v v = {0, 0, 0, 0, 0, 0, 0, 0};
            if (gr < n) {
                s8v sv = *(const s8v*)(s1b + (size_t)gr * 128 + cb);
                fx4 a0 = *(const fx4*)&stats[cb];
                fx4 a1 = *(const fx4*)&stats[cb + 4];
                fx4 b0 = *(const fx4*)&stats[128 + cb];
                fx4 b1 = *(const fx4*)&stats[128 + cb + 4];
                union { s8v v; unsigned short u[8]; } o;
                #pragma unroll
                for (int u = 0; u < 4; ++u) {
                    float h0 = fmaxf(fmaf(a0[u], bf2f((unsigned short)sv[u]), b0[u]), 0.f);
                    float h1 = fmaxf(fmaf(a1[u], bf2f((unsigned short)sv[u + 4]), b1[u]), 0.f);
                    o.u[u]     = f2bf(h0);
                    o.u[u + 4] = f2bf(h1);
                }
                v = o.v;
            }
            *(s8v*)&xs[row * 40 + kq * 8] = v;
            s8v wv = *(const s8v*)(wB2p + (size_t)row * 128 + cb);
            *(s8v*)&ws[row * 40 + kq * 8] = wv;
        }
        __syncthreads();
        s8v af[4], bf[4];
        #pragma unroll
        for (int r = 0; r < 4; ++r)
            af[r] = *(const s8v*)&xs[(wr0 + r * 16 + lm) * 40 + q * 8];
        #pragma unroll
        for (int c = 0; c < 4; ++c)
            bf[c] = *(const s8v*)&ws[(wc0 + c * 16 + lm) * 40 + q * 8];
        #pragma unroll
        for (int r = 0; r < 4; ++r)
            #pragma unroll
            for (int c = 0; c < 4; ++c)
                acc[r][c] = __builtin_amdgcn_mfma_f32_16x16x32_bf16(af[r], bf[c], acc[r][c], 0, 0, 0);
    }

    // epilogue: split store (y2p fp32 / rbuf fp32 + b2l)
    #pragma unroll
    for (int c = 0; c < 4; ++c) {
        int col = wc0 + c * 16 + lm;
        float bb = (col >= 47 && col < 94) ? b2l[col - 47] : 0.f;
        #pragma unroll
        for (int r = 0; r < 4; ++r) {
            int rowb = wr0 + r * 16 + q * 4;
            #pragma unroll
            for (int i = 0; i < 4; ++i) {
                int gr = r0 + rowb + i;
                if (gr >= n) continue;
                float v = acc[r][c][i];
                if (col < 47)      y2p[(size_t)gr * 48 + col] = v;
                else if (col < 94) rbuf[(size_t)gr * 47 + (col - 47)] = v + bb;
            }
        }
    }
}

// ---- layer-2 gather + combine + L2-norm. One wave/node, 2-edge unroll.
__global__ __launch_bounds__(256) void k_gather2_final(
        const float* __restrict__ y2p, const float* __restrict__ rbuf,
        const int* __restrict__ rowStart, const int* __restrict__ deg,
        const int* __restrict__ srcIdx, float* __restrict__ out, int n) {
    int t = threadIdx.x;
    int lane = t & 63, w = t >> 6;
    int node = blockIdx.x * 4 + w;
    if (node >= n) return;
    int beg = rowStart[node];
    int d = deg[node];
    float v = 0.f;
    if (lane < 47) {
        int end = beg + d;
        float acc0 = 0.f, acc1 = 0.f;
        int e = beg;
        for (; e + 2 <= end; e += 2) {
            int s0 = srcIdx[e];
            int s1v = srcIdx[e + 1];
            acc0 += y2p[(size_t)s0 * 48 + lane];
            acc1 += y2p[(size_t)s1v * 48 + lane];
        }
        if (e < end) acc0 += y2p[(size_t)srcIdx[e] * 48 + lane];
        v = (acc0 + acc1) / fmaxf((float)d, 1.0f) + rbuf[(size_t)node * 47 + lane];
    }
    float ss = warp_sum64(v * v);
    float inv = 1.0f / fmaxf(sqrtf(ss), 1e-12f);
    if (lane < 47) out[(size_t)node * 47 + lane] = v * inv;
}

extern "C" void kernel_launch(void* const* d_in, const int* in_sizes, int n_in,
                              void* d_out, int out_size, void* d_ws, size_t ws_size,
                              hipStream_t stream) {
    const float* x     = (const float*)d_in[0];
    const int*   ei    = (const int*)d_in[1];
    const float* w1l   = (const float*)d_in[2];
    const float* b1l   = (const float*)d_in[3];
    const float* w1r   = (const float*)d_in[4];
    const float* gamma = (const float*)d_in[5];
    const float* beta  = (const float*)d_in[6];
    const float* w2l   = (const float*)d_in[7];
    const float* b2l   = (const float*)d_in[8];
    const float* w2r   = (const float*)d_in[9];
    float* out = (float*)d_out;

    int n  = in_sizes[0] / 128;   // 100000
    int nE = in_sizes[1] / 2;     // 800000

    // ---- workspace layout ----
    // deg[n](int) | stats[256](f32) | rowStart[n] | cursor[n] | srcIdx[nE]
    // | blockSums[256] | xb[128n bf16] | aggb[128n bf16] | s1b[128n bf16]
    // | wB1[32768 bf16] | wB2p[16384 bf16]
    // y2p[48n f32] + rbuf[47n f32] overlay xb+aggb (dead after gemm1).
    int* deg       = (int*)d_ws;
    float* stats   = (float*)(deg + n);
    int* rowStart  = (int*)(stats + 256);
    int* cursor    = rowStart + n;
    int* srcIdx    = cursor + n;
    int* blockSums = srcIdx + nE;
    unsigned short* xb   = (unsigned short*)(blockSums + 256);
    unsigned short* aggb = xb + (size_t)n * 128;
    unsigned short* s1b  = aggb + (size_t)n * 128;
    unsigned short* wB1  = s1b + (size_t)n * 128;
    unsigned short* wB2p = wB1 + 32768;
    float* y2p  = (float*)xb;                 // stride 48
    float* rbuf = y2p + (size_t)n * 48;

    int nChunks = (n + 1023) / 1024;          // 98

    hipMemsetAsync(deg, 0, (size_t)n * sizeof(int) + 1024, stream);  // deg + stats

    k_wt<<<(128 * 256 + 128 * 128 + 255) / 256, 256, 0, stream>>>(w1l, w1r, w2l, w2r, wB1, wB2p);
    k_xcast<<<(n * 16 + 255) / 256, 256, 0, stream>>>(x, xb, n);
    // CSR build
    k_hist<<<(nE + 255) / 256, 256, 0, stream>>>(ei, deg, nE);
    k_scan_blocks<<<nChunks, 256, 0, stream>>>(deg, rowStart, blockSums, n);
    k_scan_sums<<<1, 256, 0, stream>>>(blockSums, nChunks);
    k_scan_add<<<nChunks, 256, 0, stream>>>(rowStart, blockSums, cursor, n);
    k_fill<<<(nE + 255) / 256, 256, 0, stream>>>(ei, cursor, srcIdx, nE);
    // layer 1
    k_gather1<<<(n + 15) / 16, 256, 0, stream>>>(xb, rowStart, deg, srcIdx, aggb, n);
    k_gemm1<<<(n + 127) / 128, 256, 0, stream>>>(xb, aggb, wB1, b1l, s1b, stats, n);
    k_bn_final<<<1, 128, 0, stream>>>(stats, gamma, beta, n);
    // layer 2
    k_gemm2<<<(n + 127) / 128, 256, 0, stream>>>(s1b, wB2p, stats, b2l, y2p, rbuf, n);
    k_gather2_final<<<(n + 3) / 4, 256, 0, stream>>>(y2p, rbuf, rowStart, deg, srcIdx, out, n);
}

// Round 7
// 356.821 us; speedup vs baseline: 7.7690x; 1.0376x over previous
//
#include <hip/hip_runtime.h>
#include <cstdint>

// GNN: 2-layer GraphSAGE (mean aggr, L2-normalize) + BatchNorm(train) + ReLU.
// N=100000 nodes, E=800000 edges, C: 128 -> 128 -> 47.
//
// Round 7:
//  - y2 carried as bf16 (stride-48 shorts): gather2 edge-row 188 B -> 94 B,
//    buffer 19.2 -> 9.6 MB. R6 showed gather2 fetching 102 MB vs 19.2 MB
//    resident = L2-miss bound; traffic halves.
//  - gathers unrolled 4 edges deep, 4 independent accumulators (16
//    outstanding loads/wave) to cover ~200-900 cyc L2/HBM miss latency.
//  - xcast + weight-cast + degree-histogram merged into one k_prep kernel.
//  - GEMMs: bf16 MFMA 16x16x32 (R6 structure, unchanged — fp32 VALU ceiling
//    was measured at 111 TF in R5; MFMA bypasses it).

typedef __attribute__((ext_vector_type(8))) short s8v;
typedef __attribute__((ext_vector_type(4))) float fx4;

static __device__ __forceinline__ float bf2f(unsigned short h) {
    union { unsigned int u; float f; } c; c.u = (unsigned int)h << 16; return c.f;
}
static __device__ __forceinline__ unsigned short f2bf(float f) {
    union { float f; unsigned int u; } c; c.f = f;
    unsigned int u = c.u;
    return (unsigned short)((u + 0x7FFF + ((u >> 16) & 1)) >> 16);   // RNE
}

static __device__ __forceinline__ float warp_sum64(float v) {
    #pragma unroll
    for (int off = 32; off > 0; off >>= 1) v += __shfl_xor(v, off, 64);
    return v;
}

// ---- merged prep: x->bf16 cast | weight bf16 transposes | degree histogram.
// ranges: [0, n*16)               xcast (one s8v per thread)
//         [n*16, +32768)          wB1[j][k] (k<128: w1l, else w1r)
//         [.., +16384)            wB2p[j][k] (j<47: w2l, j<94: w2r, else 0)
//         [.., +nE)               deg histogram
__global__ __launch_bounds__(256) void k_prep(
        const float* __restrict__ x, const float* __restrict__ w1l,
        const float* __restrict__ w1r, const float* __restrict__ w2l,
        const float* __restrict__ w2r, const int* __restrict__ ei,
        unsigned short* __restrict__ xb, unsigned short* __restrict__ wB1,
        unsigned short* __restrict__ wB2p, int* __restrict__ deg,
        int n, int nE) {
    int idx = blockIdx.x * 256 + threadIdx.x;
    int nx = n * 16;
    if (idx < nx) {
        float4 a = ((const float4*)x)[idx * 2];
        float4 b = ((const float4*)x)[idx * 2 + 1];
        union { s8v v; unsigned short u[8]; } o;
        o.u[0] = f2bf(a.x); o.u[1] = f2bf(a.y); o.u[2] = f2bf(a.z); o.u[3] = f2bf(a.w);
        o.u[4] = f2bf(b.x); o.u[5] = f2bf(b.y); o.u[6] = f2bf(b.z); o.u[7] = f2bf(b.w);
        ((s8v*)xb)[idx] = o.v;
        return;
    }
    idx -= nx;
    if (idx < 32768) {
        int j = idx >> 8, k = idx & 255;
        float v = (k < 128) ? w1l[j * 128 + k] : w1r[j * 128 + (k - 128)];
        wB1[idx] = f2bf(v);
        return;
    }
    idx -= 32768;
    if (idx < 16384) {
        int j = idx >> 7, k = idx & 127;
        float v = 0.f;
        if (j < 47)      v = w2l[j * 128 + k];
        else if (j < 94) v = w2r[(j - 47) * 128 + k];
        wB2p[idx] = f2bf(v);
        return;
    }
    idx -= 16384;
    if (idx < nE) atomicAdd(&deg[ei[nE + idx]], 1);
}

// ---- CSR build ----------------------------------------------------------
__global__ __launch_bounds__(256) void k_scan_blocks(
        const int* __restrict__ deg, int* __restrict__ rowStart,
        int* __restrict__ blockSums, int n) {
    int t = threadIdx.x;
    int base = blockIdx.x * 1024 + t * 4;
    int v[4]; int s = 0;
    #pragma unroll
    for (int u = 0; u < 4; ++u) { v[u] = (base + u < n) ? deg[base + u] : 0; s += v[u]; }
    __shared__ int sh[256];
    sh[t] = s;
    __syncthreads();
    for (int off = 1; off < 256; off <<= 1) {
        int add = (t >= off) ? sh[t - off] : 0;
        __syncthreads();
        sh[t] += add;
        __syncthreads();
    }
    int excl = sh[t] - s;
    #pragma unroll
    for (int u = 0; u < 4; ++u) { if (base + u < n) rowStart[base + u] = excl; excl += v[u]; }
    if (t == 255) blockSums[blockIdx.x] = sh[255];
}

__global__ void k_scan_sums(int* blockSums, int nb) {
    __shared__ int sh[256];
    int t = threadIdx.x;
    int s = (t < nb) ? blockSums[t] : 0;
    sh[t] = s;
    __syncthreads();
    for (int off = 1; off < 256; off <<= 1) {
        int add = (t >= off) ? sh[t - off] : 0;
        __syncthreads();
        sh[t] += add;
        __syncthreads();
    }
    if (t < nb) blockSums[t] = sh[t] - s;  // exclusive
}

__global__ __launch_bounds__(256) void k_scan_add(
        int* __restrict__ rowStart, const int* __restrict__ blockSums,
        int* __restrict__ cursor, int n) {
    int off = blockSums[blockIdx.x];
    #pragma unroll
    for (int u = 0; u < 4; ++u) {
        int i = blockIdx.x * 1024 + threadIdx.x + u * 256;
        if (i < n) { int r = rowStart[i] + off; rowStart[i] = r; cursor[i] = r; }
    }
}

__global__ __launch_bounds__(256) void k_fill(
        const int* __restrict__ ei, int* __restrict__ cursor,
        int* __restrict__ srcIdx, int nE) {
    int g = blockIdx.x * 256 + threadIdx.x;
    if (g >= nE) return;
    int s = ei[g];
    int d = ei[nE + g];
    int p = atomicAdd(&cursor[d], 1);
    srcIdx[p] = s;
}

// ---- layer-1 gather (bf16): 16 lanes/node, lane owns 8 ch; 4-edge unroll.
__global__ __launch_bounds__(256) void k_gather1(
        const unsigned short* __restrict__ xb, const int* __restrict__ rowStart,
        const int* __restrict__ deg, const int* __restrict__ srcIdx,
        unsigned short* __restrict__ aggb, int n) {
    int t = threadIdx.x;
    int q = t & 15, grp = t >> 4;
    int node = blockIdx.x * 16 + grp;
    if (node >= n) return;
    int beg = rowStart[node];
    int d = deg[node];
    int end = beg + d;
    float a0[8] = {}, a1[8] = {}, a2[8] = {}, a3[8] = {};
    int e = beg;
    for (; e + 4 <= end; e += 4) {
        int s0 = srcIdx[e], s1v = srcIdx[e + 1], s2 = srcIdx[e + 2], s3 = srcIdx[e + 3];
        s8v v0 = *(const s8v*)(xb + (size_t)s0 * 128 + q * 8);
        s8v v1 = *(const s8v*)(xb + (size_t)s1v * 128 + q * 8);
        s8v v2 = *(const s8v*)(xb + (size_t)s2 * 128 + q * 8);
        s8v v3 = *(const s8v*)(xb + (size_t)s3 * 128 + q * 8);
        #pragma unroll
        for (int u = 0; u < 8; ++u) {
            a0[u] += bf2f((unsigned short)v0[u]);
            a1[u] += bf2f((unsigned short)v1[u]);
            a2[u] += bf2f((unsigned short)v2[u]);
            a3[u] += bf2f((unsigned short)v3[u]);
        }
    }
    for (; e < end; ++e) {
        s8v v0 = *(const s8v*)(xb + (size_t)srcIdx[e] * 128 + q * 8);
        #pragma unroll
        for (int u = 0; u < 8; ++u) a0[u] += bf2f((unsigned short)v0[u]);
    }
    float ic = 1.0f / fmaxf((float)d, 1.0f);
    union { s8v v; unsigned short u[8]; } o;
    #pragma unroll
    for (int u = 0; u < 8; ++u)
        o.u[u] = f2bf((a0[u] + a1[u] + a2[u] + a3[u]) * ic);
    *(s8v*)(aggb + (size_t)node * 128 + q * 8) = o.v;
}

// ---- GEMM1 (bf16 MFMA): block 128x128, K=256 (aggb then xb).
// s1b = bf16( L2norm_rows( aggm @ w1l^T + b1l + x @ w1r^T ) );
// accumulates per-channel sum/sumsq of s1 into stats (1 atomic pair/ch/block).
__global__ __launch_bounds__(256, 3) void k_gemm1(
        const unsigned short* __restrict__ xb, const unsigned short* __restrict__ aggb,
        const unsigned short* __restrict__ wB1, const float* __restrict__ b1l,
        unsigned short* __restrict__ s1b, float* __restrict__ stats, int n) {
    __shared__ __align__(16) unsigned short xs[128 * 40];   // [row][k] stride 40
    __shared__ __align__(16) unsigned short ws[128 * 40];   // [j][k]   stride 40
    int t = threadIdx.x;
    int w = t >> 6, L = t & 63;
    int q = L >> 4, lm = L & 15;
    int wr0 = (w >> 1) * 64;     // wave row base
    int wc0 = (w & 1) * 64;      // wave col base
    int r0 = blockIdx.x * 128;

    fx4 acc[4][4];
    fx4 z4 = {0.f, 0.f, 0.f, 0.f};
    #pragma unroll
    for (int r = 0; r < 4; ++r)
        #pragma unroll
        for (int c = 0; c < 4; ++c) acc[r][c] = z4;

    for (int kt = 0; kt < 8; ++kt) {
        const unsigned short* src = (kt < 4) ? aggb : xb;
        int kbase = (kt & 3) * 32;
        __syncthreads();
        #pragma unroll
        for (int it = 0; it < 2; ++it) {
            int i = t + it * 256;            // 0..511
            int row = i >> 2, kq = i & 3;
            int gr = r0 + row;
            s8v v = {0, 0, 0, 0, 0, 0, 0, 0};
            if (gr < n) v = *(const s8v*)(src + (size_t)gr * 128 + kbase + kq * 8);
            *(s8v*)&xs[row * 40 + kq * 8] = v;
            s8v wv = *(const s8v*)(wB1 + (size_t)row * 256 + kt * 32 + kq * 8);
            *(s8v*)&ws[row * 40 + kq * 8] = wv;
        }
        __syncthreads();
        s8v af[4], bf[4];
        #pragma unroll
        for (int r = 0; r < 4; ++r)
            af[r] = *(const s8v*)&xs[(wr0 + r * 16 + lm) * 40 + q * 8];
        #pragma unroll
        for (int c = 0; c < 4; ++c)
            bf[c] = *(const s8v*)&ws[(wc0 + c * 16 + lm) * 40 + q * 8];
        #pragma unroll
        for (int r = 0; r < 4; ++r)
            #pragma unroll
            for (int c = 0; c < 4; ++c)
                acc[r][c] = __builtin_amdgcn_mfma_f32_16x16x32_bf16(af[r], bf[c], acc[r][c], 0, 0, 0);
    }

    // ---- epilogue: bias -> row L2-norm -> scale -> bf16 store -> BN stats
    float bj[4];
    #pragma unroll
    for (int c = 0; c < 4; ++c) bj[c] = b1l[wc0 + c * 16 + lm];
    #pragma unroll
    for (int r = 0; r < 4; ++r)
        #pragma unroll
        for (int c = 0; c < 4; ++c) acc[r][c] += bj[c];

    fx4 pr[4];
    #pragma unroll
    for (int r = 0; r < 4; ++r) {
        fx4 p = acc[r][0] * acc[r][0];
        #pragma unroll
        for (int c = 1; c < 4; ++c) p += acc[r][c] * acc[r][c];
        #pragma unroll
        for (int off = 1; off <= 8; off <<= 1)
            #pragma unroll
            for (int i2 = 0; i2 < 4; ++i2) p[i2] += __shfl_xor(p[i2], off, 64);
        pr[r] = p;
    }

    __syncthreads();   // xs/ws free -> overlay reductions
    float* norm2 = (float*)xs;          // [128][2]
    float* invn  = (float*)xs + 256;    // [128]
    float* statS = (float*)ws;          // [128][2]
    float* statQ = (float*)ws + 256;    // [128][2]
    if (lm == 0) {
        #pragma unroll
        for (int r = 0; r < 4; ++r)
            #pragma unroll
            for (int i = 0; i < 4; ++i)
                norm2[(wr0 + r * 16 + q * 4 + i) * 2 + (w & 1)] = pr[r][i];
    }
    __syncthreads();
    if (t < 128) {
        float s = norm2[t * 2] + norm2[t * 2 + 1];
        invn[t] = 1.0f / fmaxf(sqrtf(s), 1e-12f);
    }
    __syncthreads();

    float cS[4] = {}, cQ[4] = {};
    #pragma unroll
    for (int r = 0; r < 4; ++r) {
        int rowb = wr0 + r * 16 + q * 4;
        fx4 iv = *(const fx4*)&invn[rowb];
        #pragma unroll
        for (int c = 0; c < 4; ++c) {
            fx4 v = acc[r][c] * iv;
            int col = wc0 + c * 16 + lm;
            #pragma unroll
            for (int i = 0; i < 4; ++i) {
                int gr = r0 + rowb + i;
                if (gr < n) {
                    s1b[(size_t)gr * 128 + col] = f2bf(v[i]);
                    cS[c] += v[i];
                    cQ[c] += v[i] * v[i];
                }
            }
        }
    }
    #pragma unroll
    for (int off = 16; off <= 32; off <<= 1)
        #pragma unroll
        for (int c = 0; c < 4; ++c) {
            cS[c] += __shfl_xor(cS[c], off, 64);
            cQ[c] += __shfl_xor(cQ[c], off, 64);
        }
    if (q == 0) {
        #pragma unroll
        for (int c = 0; c < 4; ++c) {
            int col = wc0 + c * 16 + lm;
            statS[col * 2 + (w >> 1)] = cS[c];
            statQ[col * 2 + (w >> 1)] = cQ[c];
        }
    }
    __syncthreads();
    if (t < 128) {
        atomicAdd(&stats[t],       statS[t * 2] + statS[t * 2 + 1]);
        atomicAdd(&stats[128 + t], statQ[t * 2] + statQ[t * 2 + 1]);
    }
}

// ---- BN coefficient finalize: stats -> (a, b) per channel
__global__ void k_bn_final(float* stats, const float* __restrict__ gamma,
                           const float* __restrict__ beta, int n) {
    int c = threadIdx.x;  // 128
    float s = stats[c], q = stats[128 + c];
    float fn = (float)n;
    float mean = s / fn;
    float var = q / fn - mean * mean;   // biased variance
    float istd = rsqrtf(var + 1e-5f);
    float a = gamma[c] * istd;
    float b = beta[c] - mean * a;
    stats[c] = a;
    stats[128 + c] = b;
}

// ---- GEMM2 (bf16 MFMA): h = relu(BN(s1b)) applied at staging.
// h @ [w2l|w2r]^T -> y2b[N,48] bf16 (j<47) + rbuf[N,47] f32 (j 47..93, +b2l).
__global__ __launch_bounds__(256, 3) void k_gemm2(
        const unsigned short* __restrict__ s1b, const unsigned short* __restrict__ wB2p,
        const float* __restrict__ stats, const float* __restrict__ b2l,
        unsigned short* __restrict__ y2b, float* __restrict__ rbuf, int n) {
    __shared__ __align__(16) unsigned short xs[128 * 40];
    __shared__ __align__(16) unsigned short ws[128 * 40];
    int t = threadIdx.x;
    int w = t >> 6, L = t & 63;
    int q = L >> 4, lm = L & 15;
    int wr0 = (w >> 1) * 64, wc0 = (w & 1) * 64;
    int r0 = blockIdx.x * 128;

    fx4 acc[4][4];
    fx4 z4 = {0.f, 0.f, 0.f, 0.f};
    #pragma unroll
    for (int r = 0; r < 4; ++r)
        #pragma unroll
        for (int c = 0; c < 4; ++c) acc[r][c] = z4;

    for (int kt = 0; kt < 4; ++kt) {
        int kbase = kt * 32;
        __syncthreads();
        #pragma unroll
        for (int it = 0; it < 2; ++it) {
            int i = t + it * 256;
            int row = i >> 2, kq = i & 3;
            int gr = r0 + row;
            int cb = kbase + kq * 8;
            s8v v = {0, 0, 0, 0, 0, 0, 0, 0};
            if (gr < n) {
                s8v sv = *(const s8v*)(s1b + (size_t)gr * 128 + cb);
                fx4 a0 = *(const fx4*)&stats[cb];
                fx4 a1 = *(const fx4*)&stats[cb + 4];
                fx4 b0 = *(const fx4*)&stats[128 + cb];
                fx4 b1 = *(const fx4*)&stats[128 + cb + 4];
                union { s8v v; unsigned short u[8]; } o;
                #pragma unroll
                for (int u = 0; u < 4; ++u) {
                    float h0 = fmaxf(fmaf(a0[u], bf2f((unsigned short)sv[u]), b0[u]), 0.f);
                    float h1 = fmaxf(fmaf(a1[u], bf2f((unsigned short)sv[u + 4]), b1[u]), 0.f);
                    o.u[u]     = f2bf(h0);
                    o.u[u + 4] = f2bf(h1);
                }
                v = o.v;
            }
            *(s8v*)&xs[row * 40 + kq * 8] = v;
            s8v wv = *(const s8v*)(wB2p + (size_t)row * 128 + cb);
            *(s8v*)&ws[row * 40 + kq * 8] = wv;
        }
        __syncthreads();
        s8v af[4], bf[4];
        #pragma unroll
        for (int r = 0; r < 4; ++r)
            af[r] = *(const s8v*)&xs[(wr0 + r * 16 + lm) * 40 + q * 8];
        #pragma unroll
        for (int c = 0; c < 4; ++c)
            bf[c] = *(const s8v*)&ws[(wc0 + c * 16 + lm) * 40 + q * 8];
        #pragma unroll
        for (int r = 0; r < 4; ++r)
            #pragma unroll
            for (int c = 0; c < 4; ++c)
                acc[r][c] = __builtin_amdgcn_mfma_f32_16x16x32_bf16(af[r], bf[c], acc[r][c], 0, 0, 0);
    }

    // epilogue: y2b bf16 (j<47) / rbuf fp32 + b2l (j 47..93)
    #pragma unroll
    for (int c = 0; c < 4; ++c) {
        int col = wc0 + c * 16 + lm;
        float bb = (col >= 47 && col < 94) ? b2l[col - 47] : 0.f;
        #pragma unroll
        for (int r = 0; r < 4; ++r) {
            int rowb = wr0 + r * 16 + q * 4;
            #pragma unroll
            for (int i = 0; i < 4; ++i) {
                int gr = r0 + rowb + i;
                if (gr >= n) continue;
                float v = acc[r][c][i];
                if (col < 47)      y2b[(size_t)gr * 48 + col] = f2bf(v);
                else if (col < 94) rbuf[(size_t)gr * 47 + (col - 47)] = v + bb;
            }
        }
    }
}

// ---- layer-2 gather + combine + L2-norm. One wave/node, 4-edge unroll.
__global__ __launch_bounds__(256) void k_gather2_final(
        const unsigned short* __restrict__ y2b, const float* __restrict__ rbuf,
        const int* __restrict__ rowStart, const int* __restrict__ deg,
        const int* __restrict__ srcIdx, float* __restrict__ out, int n) {
    int t = threadIdx.x;
    int lane = t & 63, w = t >> 6;
    int node = blockIdx.x * 4 + w;
    if (node >= n) return;
    int beg = rowStart[node];
    int d = deg[node];
    float v = 0.f;
    if (lane < 47) {
        int end = beg + d;
        float acc0 = 0.f, acc1 = 0.f, acc2 = 0.f, acc3 = 0.f;
        int e = beg;
        for (; e + 4 <= end; e += 4) {
            int s0 = srcIdx[e], s1v = srcIdx[e + 1], s2 = srcIdx[e + 2], s3 = srcIdx[e + 3];
            acc0 += bf2f(y2b[(size_t)s0 * 48 + lane]);
            acc1 += bf2f(y2b[(size_t)s1v * 48 + lane]);
            acc2 += bf2f(y2b[(size_t)s2 * 48 + lane]);
            acc3 += bf2f(y2b[(size_t)s3 * 48 + lane]);
        }
        for (; e < end; ++e) acc0 += bf2f(y2b[(size_t)srcIdx[e] * 48 + lane]);
        v = (acc0 + acc1 + acc2 + acc3) / fmaxf((float)d, 1.0f)
            + rbuf[(size_t)node * 47 + lane];
    }
    float ss = warp_sum64(v * v);
    float inv = 1.0f / fmaxf(sqrtf(ss), 1e-12f);
    if (lane < 47) out[(size_t)node * 47 + lane] = v * inv;
}

extern "C" void kernel_launch(void* const* d_in, const int* in_sizes, int n_in,
                              void* d_out, int out_size, void* d_ws, size_t ws_size,
                              hipStream_t stream) {
    const float* x     = (const float*)d_in[0];
    const int*   ei    = (const int*)d_in[1];
    const float* w1l   = (const float*)d_in[2];
    const float* b1l   = (const float*)d_in[3];
    const float* w1r   = (const float*)d_in[4];
    const float* gamma = (const float*)d_in[5];
    const float* beta  = (const float*)d_in[6];
    const float* w2l   = (const float*)d_in[7];
    const float* b2l   = (const float*)d_in[8];
    const float* w2r   = (const float*)d_in[9];
    float* out = (float*)d_out;

    int n  = in_sizes[0] / 128;   // 100000
    int nE = in_sizes[1] / 2;     // 800000

    // ---- workspace layout ----
    // deg[n](int) | stats[256](f32) | rowStart[n] | cursor[n] | srcIdx[nE]
    // | blockSums[256] | xb[128n bf16] | aggb[128n bf16] | s1b[128n bf16]
    // | wB1[32768 bf16] | wB2p[16384 bf16]
    // y2b[48n bf16] + rbuf[47n f32] overlay xb+aggb (dead after gemm1).
    int* deg       = (int*)d_ws;
    float* stats   = (float*)(deg + n);
    int* rowStart  = (int*)(stats + 256);
    int* cursor    = rowStart + n;
    int* srcIdx    = cursor + n;
    int* blockSums = srcIdx + nE;
    unsigned short* xb   = (unsigned short*)(blockSums + 256);
    unsigned short* aggb = xb + (size_t)n * 128;
    unsigned short* s1b  = aggb + (size_t)n * 128;
    unsigned short* wB1  = s1b + (size_t)n * 128;
    unsigned short* wB2p = wB1 + 32768;
    unsigned short* y2b  = xb;                       // stride 48 shorts
    float* rbuf = (float*)(y2b + (size_t)n * 48);

    int nChunks = (n + 1023) / 1024;          // 98
    int prepTotal = n * 16 + 32768 + 16384 + nE;

    hipMemsetAsync(deg, 0, (size_t)n * sizeof(int) + 1024, stream);  // deg + stats

    k_prep<<<(prepTotal + 255) / 256, 256, 0, stream>>>(
        x, w1l, w1r, w2l, w2r, ei, xb, wB1, wB2p, deg, n, nE);
    // CSR build
    k_scan_blocks<<<nChunks, 256, 0, stream>>>(deg, rowStart, blockSums, n);
    k_scan_sums<<<1, 256, 0, stream>>>(blockSums, nChunks);
    k_scan_add<<<nChunks, 256, 0, stream>>>(rowStart, blockSums, cursor, n);
    k_fill<<<(nE + 255) / 256, 256, 0, stream>>>(ei, cursor, srcIdx, nE);
    // layer 1
    k_gather1<<<(n + 15) / 16, 256, 0, stream>>>(xb, rowStart, deg, srcIdx, aggb, n);
    k_gemm1<<<(n + 127) / 128, 256, 0, stream>>>(xb, aggb, wB1, b1l, s1b, stats, n);
    k_bn_final<<<1, 128, 0, stream>>>(stats, gamma, beta, n);
    // layer 2
    k_gemm2<<<(n + 127) / 128, 256, 0, stream>>>(s1b, wB2p, stats, b2l, y2b, rbuf, n);
    k_gather2_final<<<(n + 3) / 4, 256, 0, stream>>>(y2b, rbuf, rowStart, deg, srcIdx, out, n);
}

// Round 8
// 348.270 us; speedup vs baseline: 7.9597x; 1.0246x over previous
//
#include <hip/hip_runtime.h>
#include <cstdint>

// GNN: 2-layer GraphSAGE (mean aggr, L2-normalize) + BatchNorm(train) + ReLU.
// N=100000 nodes, E=800000 edges, C: 128 -> 128 -> 47.
//
// Round 8: CSR build rewritten as bucketed counting sort (coalesced writes).
// R7's k_fill did 800K random 4B stores -> 54 MB write-allocate thrash for a
// 3.2 MB buffer (17x amplification) + 800K contended global atomics.
// Now: chunk LDS histograms -> 1-block meta scan -> bucket-contiguous packed
// fill ((src<<8)|(dst&255), src<2^17) -> per-bucket LDS placement, all
// global writes coalesced. deg/rowStart emitted by k_csr (no memset, no
// global scans). GEMMs: bf16 MFMA 16x16x32 (fp32 VALU ceiling measured
// 111 TF in R5; MFMA bypasses it). Gathers: 4-edge unroll, bf16 payloads.

typedef __attribute__((ext_vector_type(8))) short s8v;
typedef __attribute__((ext_vector_type(4))) float fx4;

#define CSR_CHUNK 8192
#define CSR_SH 8            // 256 nodes per bucket
#define CSR_NBPAD 512       // padded bucket count (NB = ceil(n/256) = 391)
#define CSR_BUFCAP 3072     // LDS srcbuf cap per bucket (mean 2046, +20 sigma)

static __device__ __forceinline__ float bf2f(unsigned short h) {
    union { unsigned int u; float f; } c; c.u = (unsigned int)h << 16; return c.f;
}
static __device__ __forceinline__ unsigned short f2bf(float f) {
    union { float f; unsigned int u; } c; c.f = f;
    unsigned int u = c.u;
    return (unsigned short)((u + 0x7FFF + ((u >> 16) & 1)) >> 16);   // RNE
}

static __device__ __forceinline__ float warp_sum64(float v) {
    #pragma unroll
    for (int off = 32; off > 0; off >>= 1) v += __shfl_xor(v, off, 64);
    return v;
}

// ---- merged prep: x->bf16 cast | weight bf16 transposes.
__global__ __launch_bounds__(256) void k_prep(
        const float* __restrict__ x, const float* __restrict__ w1l,
        const float* __restrict__ w1r, const float* __restrict__ w2l,
        const float* __restrict__ w2r,
        unsigned short* __restrict__ xb, unsigned short* __restrict__ wB1,
        unsigned short* __restrict__ wB2p, int n) {
    int idx = blockIdx.x * 256 + threadIdx.x;
    int nx = n * 16;
    if (idx < nx) {
        float4 a = ((const float4*)x)[idx * 2];
        float4 b = ((const float4*)x)[idx * 2 + 1];
        union { s8v v; unsigned short u[8]; } o;
        o.u[0] = f2bf(a.x); o.u[1] = f2bf(a.y); o.u[2] = f2bf(a.z); o.u[3] = f2bf(a.w);
        o.u[4] = f2bf(b.x); o.u[5] = f2bf(b.y); o.u[6] = f2bf(b.z); o.u[7] = f2bf(b.w);
        ((s8v*)xb)[idx] = o.v;
        return;
    }
    idx -= nx;
    if (idx < 32768) {
        int j = idx >> 8, k = idx & 255;
        float v = (k < 128) ? w1l[j * 128 + k] : w1r[j * 128 + (k - 128)];
        wB1[idx] = f2bf(v);
        return;
    }
    idx -= 32768;
    if (idx < 16384) {
        int j = idx >> 7, k = idx & 127;
        float v = 0.f;
        if (j < 47)      v = w2l[j * 128 + k];
        else if (j < 94) v = w2r[(j - 47) * 128 + k];
        wB2p[idx] = f2bf(v);
    }
}

// ---- CSR build: bucketed counting sort -------------------------------
// Pass 1: per-chunk bucket histograms -> counts[chunk][bucket]
__global__ __launch_bounds__(256) void k_bcount(
        const int* __restrict__ ei, int* __restrict__ counts, int nE) {
    __shared__ int hist[CSR_NBPAD];
    int t = threadIdx.x;
    hist[t] = 0; hist[t + 256] = 0;
    __syncthreads();
    int e0 = blockIdx.x * CSR_CHUNK;
    int e1 = min(e0 + CSR_CHUNK, nE);
    for (int e = e0 + t; e < e1; e += 256)
        atomicAdd(&hist[ei[nE + e] >> CSR_SH], 1);
    __syncthreads();
    counts[blockIdx.x * CSR_NBPAD + t] = hist[t];
    counts[blockIdx.x * CSR_NBPAD + t + 256] = hist[t + 256];
}

// Pass 2 (1 block): bucket totals -> scan -> bucketStart; counts -> offsets.
__global__ __launch_bounds__(256) void k_bmeta(
        int* __restrict__ counts, int* __restrict__ bucketStart,
        int nE, int nCh, int NB) {
    __shared__ int tot[CSR_NBPAD], sh[256], bs[CSR_NBPAD];
    int t = threadIdx.x;
    for (int b = t; b < CSR_NBPAD; b += 256) {
        int s = 0;
        for (int c = 0; c < nCh; ++c) s += counts[c * CSR_NBPAD + b];
        tot[b] = s;
    }
    __syncthreads();
    int pairSum = tot[2 * t] + tot[2 * t + 1];
    sh[t] = pairSum;
    __syncthreads();
    for (int off = 1; off < 256; off <<= 1) {
        int add = (t >= off) ? sh[t - off] : 0;
        __syncthreads();
        sh[t] += add;
        __syncthreads();
    }
    int excl = sh[t] - pairSum;
    bs[2 * t] = excl;
    bs[2 * t + 1] = excl + tot[2 * t];
    __syncthreads();
    for (int b = t; b <= NB; b += 256) bucketStart[b] = bs[b];
    for (int b = t; b < CSR_NBPAD; b += 256) {
        int run = bs[b];
        for (int c = 0; c < nCh; ++c) {
            int v = counts[c * CSR_NBPAD + b];
            counts[c * CSR_NBPAD + b] = run;
            run += v;
        }
    }
}

// Pass 3: scatter packed (src<<8 | dst&255) into bucket-contiguous array.
__global__ __launch_bounds__(256) void k_bfill(
        const int* __restrict__ ei, const int* __restrict__ counts,
        int* __restrict__ pairs, int nE) {
    __shared__ int cur[CSR_NBPAD];
    int t = threadIdx.x;
    cur[t] = counts[blockIdx.x * CSR_NBPAD + t];
    cur[t + 256] = counts[blockIdx.x * CSR_NBPAD + t + 256];
    __syncthreads();
    int e0 = blockIdx.x * CSR_CHUNK;
    int e1 = min(e0 + CSR_CHUNK, nE);
    for (int e = e0 + t; e < e1; e += 256) {
        int s = ei[e];
        int d = ei[nE + e];
        int p = atomicAdd(&cur[d >> CSR_SH], 1);
        pairs[p] = (s << 8) | (d & 255);
    }
}

// Pass 4: one block per bucket -> deg, rowStart, srcIdx (all coalesced).
__global__ __launch_bounds__(256) void k_csr(
        const int* __restrict__ pairs, const int* __restrict__ bucketStart,
        int* __restrict__ deg, int* __restrict__ rowStart,
        int* __restrict__ srcIdx, int n) {
    __shared__ int cnt[256], scn[256], cur[256];
    __shared__ int buf[CSR_BUFCAP];
    int t = threadIdx.x;
    int bkt = blockIdx.x;
    int eBeg = bucketStart[bkt], eEnd = bucketStart[bkt + 1];
    int node0 = bkt << CSR_SH;
    cnt[t] = 0;
    __syncthreads();
    for (int e = eBeg + t; e < eEnd; e += 256)
        atomicAdd(&cnt[pairs[e] & 255], 1);
    __syncthreads();
    int myc = cnt[t];
    scn[t] = myc;
    __syncthreads();
    for (int off = 1; off < 256; off <<= 1) {
        int add = (t >= off) ? scn[t - off] : 0;
        __syncthreads();
        scn[t] += add;
        __syncthreads();
    }
    int excl = scn[t] - myc;
    cur[t] = excl;
    int node = node0 + t;
    if (node < n) { deg[node] = myc; rowStart[node] = eBeg + excl; }
    __syncthreads();
    for (int e = eBeg + t; e < eEnd; e += 256) {
        int pk = pairs[e];
        int p = atomicAdd(&cur[pk & 255], 1);
        int src = pk >> 8;
        if (p < CSR_BUFCAP) buf[p] = src;
        else srcIdx[eBeg + p] = src;   // statistically never at this size
    }
    __syncthreads();
    int m = min(eEnd - eBeg, CSR_BUFCAP);
    for (int i = t; i < m; i += 256) srcIdx[eBeg + i] = buf[i];
}

// ---- layer-1 gather (bf16): 16 lanes/node, lane owns 8 ch; 4-edge unroll.
__global__ __launch_bounds__(256) void k_gather1(
        const unsigned short* __restrict__ xb, const int* __restrict__ rowStart,
        const int* __restrict__ deg, const int* __restrict__ srcIdx,
        unsigned short* __restrict__ aggb, int n) {
    int t = threadIdx.x;
    int q = t & 15, grp = t >> 4;
    int node = blockIdx.x * 16 + grp;
    if (node >= n) return;
    int beg = rowStart[node];
    int d = deg[node];
    int end = beg + d;
    float a0[8] = {}, a1[8] = {}, a2[8] = {}, a3[8] = {};
    int e = beg;
    for (; e + 4 <= end; e += 4) {
        int s0 = srcIdx[e], s1v = srcIdx[e + 1], s2 = srcIdx[e + 2], s3 = srcIdx[e + 3];
        s8v v0 = *(const s8v*)(xb + (size_t)s0 * 128 + q * 8);
        s8v v1 = *(const s8v*)(xb + (size_t)s1v * 128 + q * 8);
        s8v v2 = *(const s8v*)(xb + (size_t)s2 * 128 + q * 8);
        s8v v3 = *(const s8v*)(xb + (size_t)s3 * 128 + q * 8);
        #pragma unroll
        for (int u = 0; u < 8; ++u) {
            a0[u] += bf2f((unsigned short)v0[u]);
            a1[u] += bf2f((unsigned short)v1[u]);
            a2[u] += bf2f((unsigned short)v2[u]);
            a3[u] += bf2f((unsigned short)v3[u]);
        }
    }
    for (; e < end; ++e) {
        s8v v0 = *(const s8v*)(xb + (size_t)srcIdx[e] * 128 + q * 8);
        #pragma unroll
        for (int u = 0; u < 8; ++u) a0[u] += bf2f((unsigned short)v0[u]);
    }
    float ic = 1.0f / fmaxf((float)d, 1.0f);
    union { s8v v; unsigned short u[8]; } o;
    #pragma unroll
    for (int u = 0; u < 8; ++u)
        o.u[u] = f2bf((a0[u] + a1[u] + a2[u] + a3[u]) * ic);
    *(s8v*)(aggb + (size_t)node * 128 + q * 8) = o.v;
}

// ---- GEMM1 (bf16 MFMA): block 128x128, K=256 (aggb then xb).
// s1b = bf16( L2norm_rows( aggm @ w1l^T + b1l + x @ w1r^T ) );
// accumulates per-channel sum/sumsq of s1 into stats (1 atomic pair/ch/block).
__global__ __launch_bounds__(256, 3) void k_gemm1(
        const unsigned short* __restrict__ xb, const unsigned short* __restrict__ aggb,
        const unsigned short* __restrict__ wB1, const float* __restrict__ b1l,
        unsigned short* __restrict__ s1b, float* __restrict__ stats, int n) {
    __shared__ __align__(16) unsigned short xs[128 * 40];   // [row][k] stride 40
    __shared__ __align__(16) unsigned short ws[128 * 40];   // [j][k]   stride 40
    int t = threadIdx.x;
    int w = t >> 6, L = t & 63;
    int q = L >> 4, lm = L & 15;
    int wr0 = (w >> 1) * 64;     // wave row base
    int wc0 = (w & 1) * 64;      // wave col base
    int r0 = blockIdx.x * 128;

    fx4 acc[4][4];
    fx4 z4 = {0.f, 0.f, 0.f, 0.f};
    #pragma unroll
    for (int r = 0; r < 4; ++r)
        #pragma unroll
        for (int c = 0; c < 4; ++c) acc[r][c] = z4;

    for (int kt = 0; kt < 8; ++kt) {
        const unsigned short* src = (kt < 4) ? aggb : xb;
        int kbase = (kt & 3) * 32;
        __syncthreads();
        #pragma unroll
        for (int it = 0; it < 2; ++it) {
            int i = t + it * 256;            // 0..511
            int row = i >> 2, kq = i & 3;
            int gr = r0 + row;
            s8v v = {0, 0, 0, 0, 0, 0, 0, 0};
            if (gr < n) v = *(const s8v*)(src + (size_t)gr * 128 + kbase + kq * 8);
            *(s8v*)&xs[row * 40 + kq * 8] = v;
            s8v wv = *(const s8v*)(wB1 + (size_t)row * 256 + kt * 32 + kq * 8);
            *(s8v*)&ws[row * 40 + kq * 8] = wv;
        }
        __syncthreads();
        s8v af[4], bf[4];
        #pragma unroll
        for (int r = 0; r < 4; ++r)
            af[r] = *(const s8v*)&xs[(wr0 + r * 16 + lm) * 40 + q * 8];
        #pragma unroll
        for (int c = 0; c < 4; ++c)
            bf[c] = *(const s8v*)&ws[(wc0 + c * 16 + lm) * 40 + q * 8];
        #pragma unroll
        for (int r = 0; r < 4; ++r)
            #pragma unroll
            for (int c = 0; c < 4; ++c)
                acc[r][c] = __builtin_amdgcn_mfma_f32_16x16x32_bf16(af[r], bf[c], acc[r][c], 0, 0, 0);
    }

    // ---- epilogue: bias -> row L2-norm -> scale -> bf16 store -> BN stats
    float bj[4];
    #pragma unroll
    for (int c = 0; c < 4; ++c) bj[c] = b1l[wc0 + c * 16 + lm];
    #pragma unroll
    for (int r = 0; r < 4; ++r)
        #pragma unroll
        for (int c = 0; c < 4; ++c) acc[r][c] += bj[c];

    fx4 pr[4];
    #pragma unroll
    for (int r = 0; r < 4; ++r) {
        fx4 p = acc[r][0] * acc[r][0];
        #pragma unroll
        for (int c = 1; c < 4; ++c) p += acc[r][c] * acc[r][c];
        #pragma unroll
        for (int off = 1; off <= 8; off <<= 1)
            #pragma unroll
            for (int i2 = 0; i2 < 4; ++i2) p[i2] += __shfl_xor(p[i2], off, 64);
        pr[r] = p;
    }

    __syncthreads();   // xs/ws free -> overlay reductions
    float* norm2 = (float*)xs;          // [128][2]
    float* invn  = (float*)xs + 256;    // [128]
    float* statS = (float*)ws;          // [128][2]
    float* statQ = (float*)ws + 256;    // [128][2]
    if (lm == 0) {
        #pragma unroll
        for (int r = 0; r < 4; ++r)
            #pragma unroll
            for (int i = 0; i < 4; ++i)
                norm2[(wr0 + r * 16 + q * 4 + i) * 2 + (w & 1)] = pr[r][i];
    }
    __syncthreads();
    if (t < 128) {
        float s = norm2[t * 2] + norm2[t * 2 + 1];
        invn[t] = 1.0f / fmaxf(sqrtf(s), 1e-12f);
    }
    __syncthreads();

    float cS[4] = {}, cQ[4] = {};
    #pragma unroll
    for (int r = 0; r < 4; ++r) {
        int rowb = wr0 + r * 16 + q * 4;
        fx4 iv = *(const fx4*)&invn[rowb];
        #pragma unroll
        for (int c = 0; c < 4; ++c) {
            fx4 v = acc[r][c] * iv;
            int col = wc0 + c * 16 + lm;
            #pragma unroll
            for (int i = 0; i < 4; ++i) {
                int gr = r0 + rowb + i;
                if (gr < n) {
                    s1b[(size_t)gr * 128 + col] = f2bf(v[i]);
                    cS[c] += v[i];
                    cQ[c] += v[i] * v[i];
                }
            }
        }
    }
    #pragma unroll
    for (int off = 16; off <= 32; off <<= 1)
        #pragma unroll
        for (int c = 0; c < 4; ++c) {
            cS[c] += __shfl_xor(cS[c], off, 64);
            cQ[c] += __shfl_xor(cQ[c], off, 64);
        }
    if (q == 0) {
        #pragma unroll
        for (int c = 0; c < 4; ++c) {
            int col = wc0 + c * 16 + lm;
            statS[col * 2 + (w >> 1)] = cS[c];
            statQ[col * 2 + (w >> 1)] = cQ[c];
        }
    }
    __syncthreads();
    if (t < 128) {
        atomicAdd(&stats[t],       statS[t * 2] + statS[t * 2 + 1]);
        atomicAdd(&stats[128 + t], statQ[t * 2] + statQ[t * 2 + 1]);
    }
}

// ---- BN coefficient finalize: stats -> (a, b) per channel
__global__ void k_bn_final(float* stats, const float* __restrict__ gamma,
                           const float* __restrict__ beta, int n) {
    int c = threadIdx.x;  // 128
    float s = stats[c], q = stats[128 + c];
    float fn = (float)n;
    float mean = s / fn;
    float var = q / fn - mean * mean;   // biased variance
    float istd = rsqrtf(var + 1e-5f);
    float a = gamma[c] * istd;
    float b = beta[c] - mean * a;
    stats[c] = a;
    stats[128 + c] = b;
}

// ---- GEMM2 (bf16 MFMA): h = relu(BN(s1b)) applied at staging.
// h @ [w2l|w2r]^T -> y2b[N,48] bf16 (j<47) + rbuf[N,47] f32 (j 47..93, +b2l).
__global__ __launch_bounds__(256, 3) void k_gemm2(
        const unsigned short* __restrict__ s1b, const unsigned short* __restrict__ wB2p,
        const float* __restrict__ stats, const float* __restrict__ b2l,
        unsigned short* __restrict__ y2b, float* __restrict__ rbuf, int n) {
    __shared__ __align__(16) unsigned short xs[128 * 40];
    __shared__ __align__(16) unsigned short ws[128 * 40];
    int t = threadIdx.x;
    int w = t >> 6, L = t & 63;
    int q = L >> 4, lm = L & 15;
    int wr0 = (w >> 1) * 64, wc0 = (w & 1) * 64;
    int r0 = blockIdx.x * 128;

    fx4 acc[4][4];
    fx4 z4 = {0.f, 0.f, 0.f, 0.f};
    #pragma unroll
    for (int r = 0; r < 4; ++r)
        #pragma unroll
        for (int c = 0; c < 4; ++c) acc[r][c] = z4;

    for (int kt = 0; kt < 4; ++kt) {
        int kbase = kt * 32;
        __syncthreads();
        #pragma unroll
        for (int it = 0; it < 2; ++it) {
            int i = t + it * 256;
            int row = i >> 2, kq = i & 3;
            int gr = r0 + row;
            int cb = kbase + kq * 8;
            s8v v = {0, 0, 0, 0, 0, 0, 0, 0};
            if (gr < n) {
                s8v sv = *(const s8v*)(s1b + (size_t)gr * 128 + cb);
                fx4 a0 = *(const fx4*)&stats[cb];
                fx4 a1 = *(const fx4*)&stats[cb + 4];
                fx4 b0 = *(const fx4*)&stats[128 + cb];
                fx4 b1 = *(const fx4*)&stats[128 + cb + 4];
                union { s8v v; unsigned short u[8]; } o;
                #pragma unroll
                for (int u = 0; u < 4; ++u) {
                    float h0 = fmaxf(fmaf(a0[u], bf2f((unsigned short)sv[u]), b0[u]), 0.f);
                    float h1 = fmaxf(fmaf(a1[u], bf2f((unsigned short)sv[u + 4]), b1[u]), 0.f);
                    o.u[u]     = f2bf(h0);
                    o.u[u + 4] = f2bf(h1);
                }
                v = o.v;
            }
            *(s8v*)&xs[row * 40 + kq * 8] = v;
            s8v wv = *(const s8v*)(wB2p + (size_t)row * 128 + cb);
            *(s8v*)&ws[row * 40 + kq * 8] = wv;
        }
        __syncthreads();
        s8v af[4], bf[4];
        #pragma unroll
        for (int r = 0; r < 4; ++r)
            af[r] = *(const s8v*)&xs[(wr0 + r * 16 + lm) * 40 + q * 8];
        #pragma unroll
        for (int c = 0; c < 4; ++c)
            bf[c] = *(const s8v*)&ws[(wc0 + c * 16 + lm) * 40 + q * 8];
        #pragma unroll
        for (int r = 0; r < 4; ++r)
            #pragma unroll
            for (int c = 0; c < 4; ++c)
                acc[r][c] = __builtin_amdgcn_mfma_f32_16x16x32_bf16(af[r], bf[c], acc[r][c], 0, 0, 0);
    }

    // epilogue: y2b bf16 (j<47) / rbuf fp32 + b2l (j 47..93)
    #pragma unroll
    for (int c = 0; c < 4; ++c) {
        int col = wc0 + c * 16 + lm;
        float bb = (col >= 47 && col < 94) ? b2l[col - 47] : 0.f;
        #pragma unroll
        for (int r = 0; r < 4; ++r) {
            int rowb = wr0 + r * 16 + q * 4;
            #pragma unroll
            for (int i = 0; i < 4; ++i) {
                int gr = r0 + rowb + i;
                if (gr >= n) continue;
                float v = acc[r][c][i];
                if (col < 47)      y2b[(size_t)gr * 48 + col] = f2bf(v);
                else if (col < 94) rbuf[(size_t)gr * 47 + (col - 47)] = v + bb;
            }
        }
    }
}

// ---- layer-2 gather + combine + L2-norm. One wave/node, 4-edge unroll.
__global__ __launch_bounds__(256) void k_gather2_final(
        const unsigned short* __restrict__ y2b, const float* __restrict__ rbuf,
        const int* __restrict__ rowStart, const int* __restrict__ deg,
        const int* __restrict__ srcIdx, float* __restrict__ out, int n) {
    int t = threadIdx.x;
    int lane = t & 63, w = t >> 6;
    int node = blockIdx.x * 4 + w;
    if (node >= n) return;
    int beg = rowStart[node];
    int d = deg[node];
    float v = 0.f;
    if (lane < 47) {
        int end = beg + d;
        float acc0 = 0.f, acc1 = 0.f, acc2 = 0.f, acc3 = 0.f;
        int e = beg;
        for (; e + 4 <= end; e += 4) {
            int s0 = srcIdx[e], s1v = srcIdx[e + 1], s2 = srcIdx[e + 2], s3 = srcIdx[e + 3];
            acc0 += bf2f(y2b[(size_t)s0 * 48 + lane]);
            acc1 += bf2f(y2b[(size_t)s1v * 48 + lane]);
            acc2 += bf2f(y2b[(size_t)s2 * 48 + lane]);
            acc3 += bf2f(y2b[(size_t)s3 * 48 + lane]);
        }
        for (; e < end; ++e) acc0 += bf2f(y2b[(size_t)srcIdx[e] * 48 + lane]);
        v = (acc0 + acc1 + acc2 + acc3) / fmaxf((float)d, 1.0f)
            + rbuf[(size_t)node * 47 + lane];
    }
    float ss = warp_sum64(v * v);
    float inv = 1.0f / fmaxf(sqrtf(ss), 1e-12f);
    if (lane < 47) out[(size_t)node * 47 + lane] = v * inv;
}

extern "C" void kernel_launch(void* const* d_in, const int* in_sizes, int n_in,
                              void* d_out, int out_size, void* d_ws, size_t ws_size,
                              hipStream_t stream) {
    const float* x     = (const float*)d_in[0];
    const int*   ei    = (const int*)d_in[1];
    const float* w1l   = (const float*)d_in[2];
    const float* b1l   = (const float*)d_in[3];
    const float* w1r   = (const float*)d_in[4];
    const float* gamma = (const float*)d_in[5];
    const float* beta  = (const float*)d_in[6];
    const float* w2l   = (const float*)d_in[7];
    const float* b2l   = (const float*)d_in[8];
    const float* w2r   = (const float*)d_in[9];
    float* out = (float*)d_out;

    int n  = in_sizes[0] / 128;   // 100000
    int nE = in_sizes[1] / 2;     // 800000

    int NB  = (n + 255) >> 8;                 // 391 buckets
    int nCh = (nE + CSR_CHUNK - 1) / CSR_CHUNK;  // 98 chunks

    // ---- workspace layout ----
    // deg[n](int) | stats[256](f32) | rowStart[n] | meta[n] | srcIdx[nE]
    // | xb[128n bf16] | aggb[128n bf16] | s1b[128n bf16] | wB1 | wB2p
    // meta holds counts[nCh*512] (<= 50176 ints) then bucketStart[NB+1] at +60000.
    // pairs[nE] (packed ints) overlays s1b (dead until gemm1).
    // y2b[48n bf16] + rbuf[47n f32] overlay xb (dead after gemm1).
    int* deg       = (int*)d_ws;
    float* stats   = (float*)(deg + n);
    int* rowStart  = (int*)(stats + 256);
    int* meta      = rowStart + n;
    int* srcIdx    = meta + n;
    unsigned short* xb   = (unsigned short*)(srcIdx + nE);
    unsigned short* aggb = xb + (size_t)n * 128;
    unsigned short* s1b  = aggb + (size_t)n * 128;
    unsigned short* wB1  = s1b + (size_t)n * 128;
    unsigned short* wB2p = wB1 + 32768;
    int* counts      = meta;
    int* bucketStart = meta + 60000;
    int* pairs       = (int*)s1b;             // packed (src<<8)|(dst&255)
    unsigned short* y2b = xb;                 // stride 48 shorts
    float* rbuf = (float*)(y2b + (size_t)n * 48);

    int prepTotal = n * 16 + 32768 + 16384;

    hipMemsetAsync(stats, 0, 1024, stream);

    k_prep<<<(prepTotal + 255) / 256, 256, 0, stream>>>(
        x, w1l, w1r, w2l, w2r, xb, wB1, wB2p, n);
    // CSR build (bucketed counting sort)
    k_bcount<<<nCh, 256, 0, stream>>>(ei, counts, nE);
    k_bmeta<<<1, 256, 0, stream>>>(counts, bucketStart, nE, nCh, NB);
    k_bfill<<<nCh, 256, 0, stream>>>(ei, counts, pairs, nE);
    k_csr<<<NB, 256, 0, stream>>>(pairs, bucketStart, deg, rowStart, srcIdx, n);
    // layer 1
    k_gather1<<<(n + 15) / 16, 256, 0, stream>>>(xb, rowStart, deg, srcIdx, aggb, n);
    k_gemm1<<<(n + 127) / 128, 256, 0, stream>>>(xb, aggb, wB1, b1l, s1b, stats, n);
    k_bn_final<<<1, 128, 0, stream>>>(stats, gamma, beta, n);
    // layer 2
    k_gemm2<<<(n + 127) / 128, 256, 0, stream>>>(s1b, wB2p, stats, b2l, y2b, rbuf, n);
    k_gather2_final<<<(n + 3) / 4, 256, 0, stream>>>(y2b, rbuf, rowStart, deg, srcIdx, out, n);
}